// Round 1
// 421.912 us; speedup vs baseline: 1.1080x; 1.1080x over previous
//
#include <hip/hip_runtime.h>

// DeSELayer: per-sample CP-ALS(rank4, 20 it) -> rank_fc -> SE fc -> sigmoid gate.
// Gram-trick: iterations run on Gram = T0^T T0 (196x196).
// 1 workgroup (1024 thr) per sample; grid = 256 = #CUs.
// R3: phase-1 Gram via MFMA split-bf16.
// R4: phase-2 Y = Gram*H via MFMA too. After phase 1, wave J (J<13) holds
//     A-frags of Gram row-block J (bf16 hi/lo, 56 VGPR, K=224 padded) built
//     once from the LDS gram square; per iteration H is scattered (wave 0)
//     into bf16 B-fragments in LDS (aliasing the dead gram region) and each
//     wave does 7x3 mfma_16x16x32_bf16 -> plain Y stores. Removes the
//     196-FMA+196-readlane scalar Y loop, LDS atomics, and Y zero-fill.
//     Epilogue GEMV split across all 1024 threads (2 per channel).

#define EPSV 1e-6f

#define SM_G    0
#define SM_COF  16
#define SM_GINV 32
#define SM_M    48
#define SM_ATA  104

typedef __attribute__((ext_vector_type(8))) short short8;
typedef __attribute__((ext_vector_type(4))) float float4v;

struct SMem {
  union {
    struct {                      // ---- phase 1 ----
      short xhi[4 * 13 * 64 * 8]; // frag-order: [kstep s][tile T][lane][8 ch] bf16
      short xlo[4 * 13 * 64 * 8]; // 53,248 B each
      float stage_f[64 * 200];    // 51,200 B transpose staging (64 ch x 196 p)
    } p1;
    struct {                      // ---- phase 2 ----
      union {
        float gram[196 * 197];    // 154,448 B; dead after A-frag build
        struct {                  // live after A-frag build
          short fh[7 * 64 * 8];   // H B-fragments bf16 hi: [kb][lane][8]
          short fl[7 * 64 * 8];   // H B-fragments bf16 lo
          float part[512 * 5];    // epilogue partial sums (stride 5)
        } f;
      } g;
      float H[196 * 5];           // stride 5
      float Y[196 * 5];           // stride 5; epilogue: y[512] @0, z[32] @512
    } p2;
  } u;
  float B[56];                    // B[j][r] flat j*4+r
  float C[56];
  float Sm[120];                  // G,COF,GINV,M(56),ATA
};

__device__ __forceinline__ float rlane(float v, int l) {
  return __uint_as_float(__builtin_amdgcn_readlane(__float_as_uint(v), l));
}
__device__ __forceinline__ void fence_lds() { __threadfence_block(); }

// round-to-nearest-even fp32 -> bf16 (returned in low 16 bits)
__device__ __forceinline__ unsigned bf16rne(float f) {
  unsigned u = __float_as_uint(f);
  return (u + 0x7FFFu + ((u >> 16) & 1u)) >> 16;
}

// (V^T V)[r][s] for lanes (meaningful for l<16); V = 14x4 flat
__device__ __forceinline__ float gram16(const float* V, int l) {
  int r = (l >> 2) & 3, s = l & 3;
  float a = 0.f;
#pragma unroll
  for (int j = 0; j < 14; ++j) a += V[j * 4 + r] * V[j * 4 + s];
  return a;
}

// lanes 0..15 of wave 0: Sm[G..G+15] -> Sm[GINV..] via adjugate (G symmetric SPD + eps)
__device__ __forceinline__ void inv4x4(SMem* sm, int l) {
  if (l < 16) {
    float g[16];
#pragma unroll
    for (int t = 0; t < 16; ++t) g[t] = sm->Sm[SM_G + t];
    int r = l >> 2, s = l & 3;
    int r0 = (r == 0) ? 1 : 0, r1 = (r <= 1) ? 2 : 1, r2 = (r <= 2) ? 3 : 2;
    int c0 = (s == 0) ? 1 : 0, c1 = (s <= 1) ? 2 : 1, c2 = (s <= 2) ? 3 : 2;
    float a00 = g[r0 * 4 + c0], a01 = g[r0 * 4 + c1], a02 = g[r0 * 4 + c2];
    float a10 = g[r1 * 4 + c0], a11 = g[r1 * 4 + c1], a12 = g[r1 * 4 + c2];
    float a20 = g[r2 * 4 + c0], a21 = g[r2 * 4 + c1], a22 = g[r2 * 4 + c2];
    float d3 = a00 * (a11 * a22 - a12 * a21) - a01 * (a10 * a22 - a12 * a20)
             + a02 * (a10 * a21 - a11 * a20);
    sm->Sm[SM_COF + l] = ((r + s) & 1) ? -d3 : d3;
  }
  fence_lds();
  if (l < 16) {
    float det = sm->Sm[SM_G + 0] * sm->Sm[SM_COF + 0] + sm->Sm[SM_G + 1] * sm->Sm[SM_COF + 1]
              + sm->Sm[SM_G + 2] * sm->Sm[SM_COF + 2] + sm->Sm[SM_G + 3] * sm->Sm[SM_COF + 3];
    int r = l >> 2, s = l & 3;
    sm->Sm[SM_GINV + l] = sm->Sm[SM_COF + s * 4 + r] / det;  // adj = cof^T
  }
  fence_lds();
}

// wave 0: H[p][r] = sum_s B[j][s]C[k][s] * Ginv[s][r].
// Writes fp32 H (stride 5) AND scatters bf16 hi/lo into the B-fragment
// arrays fh/fl. B-frag layout (16x16x32): lane l holds B[k=(l>>4)*8+i, col=l&15];
// element (p,r) -> kb=p>>5, lane=((p>>3)&3)*16+r, i=p&7. Pads stay zero
// (zero-filled once before first call).
__device__ __forceinline__ void computeH_scatter(SMem* sm, int l) {
#pragma unroll
  for (int k4 = 0; k4 < 4; ++k4) {
    int p = l + 64 * k4;
    if (p < 196) {
      int j = p / 14, kk = p - j * 14;
      float kr[4];
#pragma unroll
      for (int s = 0; s < 4; ++s) kr[s] = sm->B[j * 4 + s] * sm->C[kk * 4 + s];
      int kb = p >> 5, ii = p & 7, lrow = ((p >> 3) & 3) * 16;
#pragma unroll
      for (int r = 0; r < 4; ++r) {
        float h = kr[0] * sm->Sm[SM_GINV + 0 + r] + kr[1] * sm->Sm[SM_GINV + 4 + r]
                + kr[2] * sm->Sm[SM_GINV + 8 + r] + kr[3] * sm->Sm[SM_GINV + 12 + r];
        sm->u.p2.H[p * 5 + r] = h;
        unsigned hh = bf16rne(h);
        float hf = __uint_as_float(hh << 16);
        unsigned ll = bf16rne(h - hf);
        int fi = (kb * 64 + lrow + r) * 8 + ii;
        sm->u.p2.g.f.fh[fi] = (short)hh;
        sm->u.p2.g.f.fl[fi] = (short)ll;
      }
    }
  }
}

__device__ __forceinline__ void initial_H(SMem* sm, int l) {
  float btb = gram16(sm->B, l);
  float ctc = gram16(sm->C, l);
  if (l < 16) {
    float dg = ((l >> 2) == (l & 3)) ? EPSV : 0.f;
    sm->Sm[SM_G + l] = btb * ctc + dg;
  }
  fence_lds();
  inv4x4(sm, l);
  computeH_scatter(sm, l);
}

// wave 0: ATA in Sm[ATA], Y current. Updates B, C, then next H.
__device__ __forceinline__ void factor_update(SMem* sm, int l) {
  int jj = l >> 2, r = l & 3;
  float dg = ((l >> 2) == (l & 3)) ? EPSV : 0.f;
  // --- B update: G_B = ATA o CtC(old) + eps ---
  float ctc_old = gram16(sm->C, l);
  if (l < 16) sm->Sm[SM_G + l] = sm->Sm[SM_ATA + l] * ctc_old + dg;
  fence_lds();
  inv4x4(sm, l);
  if (l < 56) {
    float m = 0.f;
#pragma unroll
    for (int k = 0; k < 14; ++k) m += sm->u.p2.Y[(jj * 14 + k) * 5 + r] * sm->C[k * 4 + r];
    sm->Sm[SM_M + l] = m;
  }
  fence_lds();
  if (l < 56) {
    float bn = 0.f;
#pragma unroll
    for (int s = 0; s < 4; ++s) bn += sm->Sm[SM_M + jj * 4 + s] * sm->Sm[SM_GINV + s * 4 + r];
    sm->B[l] = bn;
  }
  fence_lds();
  // --- C update: G_C = ATA o BtB(new) + eps ---
  float btb = gram16(sm->B, l);
  if (l < 16) sm->Sm[SM_G + l] = sm->Sm[SM_ATA + l] * btb + dg;
  fence_lds();
  inv4x4(sm, l);
  if (l < 56) {
    float m = 0.f;
#pragma unroll
    for (int j = 0; j < 14; ++j) m += sm->u.p2.Y[(j * 14 + jj) * 5 + r] * sm->B[j * 4 + r];
    sm->Sm[SM_M + l] = m;
  }
  fence_lds();
  if (l < 56) {
    float cn = 0.f;
#pragma unroll
    for (int s = 0; s < 4; ++s) cn += sm->Sm[SM_M + jj * 4 + s] * sm->Sm[SM_GINV + s * 4 + r];
    sm->C[l] = cn;
  }
  fence_lds();
  // --- next-iteration H: G_A = BtB(new) o CtC(new) + eps ---
  float ctc_new = gram16(sm->C, l);
  if (l < 16) sm->Sm[SM_G + l] = btb * ctc_new + dg;
  fence_lds();
  inv4x4(sm, l);
  computeH_scatter(sm, l);
}

extern "C" __global__ void __launch_bounds__(1024, 4)
dese_kernel(const float* __restrict__ x, const float* __restrict__ B0,
            const float* __restrict__ C0, const float* __restrict__ w1,
            const float* __restrict__ w2, const float* __restrict__ fw1,
            const float* __restrict__ fw2, float* __restrict__ out) {
  extern __shared__ char smraw[];
  SMem* sm = (SMem*)smraw;
  const int tid = threadIdx.x;
  const int b = blockIdx.x;
  const int wv = tid >> 6;
  const int lane = tid & 63;
  const float* xb = x + (size_t)b * 100352;

  // load per-sample B0, C0 (A0 is dead: first ALS step overwrites A)
  if (tid < 56) sm->B[tid] = B0[b * 56 + tid];
  if (tid >= 64 && tid < 120) sm->C[tid - 64] = C0[b * 56 + (tid - 64)];

  // ================= Phase 1: Gram = X X^T via MFMA split-bf16 =================
  // X = T0^T (196 spatial x 512 ch), padded to 208 rows (13 tiles of 16).
  // Gram tile (I,J), I<=J: acc += hi_I*hi_J + hi_I*lo_J + lo_I*hi_J (fp32 acc).
  // 96 tile-slots over 16 waves (6 each, 91 valid). K chunked 4x128 ch.
  {
    float4v acc[6];
#pragma unroll
    for (int i = 0; i < 6; ++i) acc[i] = (float4v){0.f, 0.f, 0.f, 0.f};

    int TI[6], TJ[6], TVv[6];
#pragma unroll
    for (int i = 0; i < 6; ++i) {
      int t = wv * 6 + i;
      int valid = (t < 91);
      int I = 0, cum = 0;
      if (valid) {
        while (t >= cum + (13 - I)) { cum += (13 - I); ++I; }
      }
      TI[i] = valid ? I : 0;
      TJ[i] = valid ? (I + t - cum) : 0;
      TVv[i] = valid;
    }

    const float4* x4 = (const float4*)xb;
    for (int chunk = 0; chunk < 4; ++chunk) {
#pragma unroll
      for (int slab = 0; slab < 2; ++slab) {
        const int cb = chunk * 128 + slab * 64;   // base channel of 64-ch slab
        __syncthreads();  // prev MFMA/transpose readers done
        // ---- global -> stage_f: 64 ch x 196 p fp32, coalesced float4 ----
#pragma unroll
        for (int j = 0; j < 4; ++j) {
          int fi = tid + 1024 * j;
          if (fi < 3136) {
            int ch = fi / 49, i4 = fi - ch * 49;
            float4 v = x4[(size_t)(cb + ch) * 49 + i4];
            *(float4*)&sm->u.p1.stage_f[ch * 200 + i4 * 4] = v;
          }
        }
        __syncthreads();
        // ---- transpose + hi/lo split -> fragment-order bf16 ----
        int p = tid & 255, chgrp = tid >> 8;      // p: spatial row; chgrp: 16-ch group
        if (p < 208) {
#pragma unroll
          for (int oct = 0; oct < 2; ++oct) {
            unsigned hp[4], lp[4];
#pragma unroll
            for (int ii = 0; ii < 8; ++ii) {
              int ch = chgrp * 16 + oct * 8 + ii;
              float v = (p < 196) ? sm->u.p1.stage_f[ch * 200 + p] : 0.f;
              unsigned h = bf16rne(v);
              float hf = __uint_as_float(h << 16);
              unsigned l = bf16rne(v - hf);
              if (ii & 1) { hp[ii >> 1] |= (h << 16); lp[ii >> 1] |= (l << 16); }
              else        { hp[ii >> 1] = h;          lp[ii >> 1] = l; }
            }
            int o = slab * 8 + chgrp * 2 + oct;   // ch-octet index within 128-chunk
            int fidx = ((o >> 2) * 13 + (p >> 4)) * 64 + (((o & 3) << 4) | (p & 15));
            *(uint4*)&sm->u.p1.xhi[fidx * 8] = make_uint4(hp[0], hp[1], hp[2], hp[3]);
            *(uint4*)&sm->u.p1.xlo[fidx * 8] = make_uint4(lp[0], lp[1], lp[2], lp[3]);
          }
        }
      }
      __syncthreads();  // XTfrag chunk complete
      // ---- MFMA: 4 ksteps (K=32 each) x 6 tiles; contiguous-1KB b128 frag reads ----
#pragma unroll
      for (int s = 0; s < 4; ++s) {
#pragma unroll
        for (int ti = 0; ti < 6; ++ti) {
          const short8 aH = *(const short8*)&sm->u.p1.xhi[((s * 13 + TI[ti]) * 64 + lane) * 8];
          const short8 aL = *(const short8*)&sm->u.p1.xlo[((s * 13 + TI[ti]) * 64 + lane) * 8];
          const short8 bH = *(const short8*)&sm->u.p1.xhi[((s * 13 + TJ[ti]) * 64 + lane) * 8];
          const short8 bL = *(const short8*)&sm->u.p1.xlo[((s * 13 + TJ[ti]) * 64 + lane) * 8];
          acc[ti] = __builtin_amdgcn_mfma_f32_16x16x32_bf16(aH, bH, acc[ti], 0, 0, 0);
          acc[ti] = __builtin_amdgcn_mfma_f32_16x16x32_bf16(aH, bL, acc[ti], 0, 0, 0);
          acc[ti] = __builtin_amdgcn_mfma_f32_16x16x32_bf16(aL, bH, acc[ti], 0, 0, 0);
        }
      }
    }
    __syncthreads();  // all MFMA frag reads done; p1 region now dead
    // ---- write acc -> gram (C/D layout: col=lane&15, row=quad*4+reg) + mirror ----
    {
      int col = lane & 15, quad = lane >> 4;
#pragma unroll
      for (int ti = 0; ti < 6; ++ti) {
        if (TVv[ti]) {
#pragma unroll
          for (int reg = 0; reg < 4; ++reg) {
            int pr = TI[ti] * 16 + quad * 4 + reg;
            int pc = TJ[ti] * 16 + col;
            if (pr < 196 && pc < 196) {
              float v = acc[ti][reg];
              sm->u.p2.g.gram[pr * 197 + pc] = v;
              sm->u.p2.g.gram[pc * 197 + pr] = v;
            }
          }
        }
      }
    }
  }
  __syncthreads();

  // ============ A-fragment build: wave J holds Gram row-block J in regs ========
  // A-frag (16x16x32): lane l, elem i -> A[m=l&15, k=(l>>4)*8+i] = G[J*16+m, kb*32+k].
  // bf16 hi/lo split; zero-padded past 196 on both m and k.
  short8 afh[7], afl[7];
  if (wv < 13) {
    const int m = wv * 16 + (lane & 15);
    const int mok = (m < 196);
    const int kq = (lane >> 4) * 8;
#pragma unroll
    for (int kb = 0; kb < 7; ++kb) {
#pragma unroll
      for (int i = 0; i < 8; ++i) {
        int k = kb * 32 + kq + i;
        float v = (mok && k < 196) ? sm->u.p2.g.gram[m * 197 + k] : 0.f;
        unsigned h = bf16rne(v);
        float hf = __uint_as_float(h << 16);
        unsigned lo = bf16rne(v - hf);
        afh[kb][i] = (short)h;
        afl[kb][i] = (short)lo;
      }
    }
  }
  __syncthreads();  // gram fully consumed; its region may now be reused
  // zero-fill H B-fragment arrays once (pads stay zero forever)
  {
    unsigned* z = (unsigned*)sm->u.p2.g.f.fh;  // fh+fl contiguous: 3584 u32
#pragma unroll
    for (int t = 0; t < 4; ++t) {
      int idx = tid + 1024 * t;
      if (idx < 3584) z[idx] = 0u;
    }
  }
  __syncthreads();

  // ================= Phase 2: 19 ALS iteration bodies on Gram =================
  if (tid < 64) initial_H(sm, lane);
  __syncthreads();

  for (int it = 0; it < 19; ++it) {
    // ---- Y[p][r] = Gram*H via MFMA: wave J -> Y rows J*16..+15, no atomics ----
    if (wv < 13) {
      float4v ac0 = {0.f, 0.f, 0.f, 0.f}, ac1 = {0.f, 0.f, 0.f, 0.f};
#pragma unroll
      for (int kb = 0; kb < 7; ++kb) {
        const short8 bh = *(const short8*)&sm->u.p2.g.f.fh[(kb * 64 + lane) * 8];
        const short8 bl = *(const short8*)&sm->u.p2.g.f.fl[(kb * 64 + lane) * 8];
        if (kb & 1) {
          ac1 = __builtin_amdgcn_mfma_f32_16x16x32_bf16(afh[kb], bh, ac1, 0, 0, 0);
          ac1 = __builtin_amdgcn_mfma_f32_16x16x32_bf16(afh[kb], bl, ac1, 0, 0, 0);
          ac1 = __builtin_amdgcn_mfma_f32_16x16x32_bf16(afl[kb], bh, ac1, 0, 0, 0);
        } else {
          ac0 = __builtin_amdgcn_mfma_f32_16x16x32_bf16(afh[kb], bh, ac0, 0, 0, 0);
          ac0 = __builtin_amdgcn_mfma_f32_16x16x32_bf16(afh[kb], bl, ac0, 0, 0, 0);
          ac0 = __builtin_amdgcn_mfma_f32_16x16x32_bf16(afl[kb], bh, ac0, 0, 0, 0);
        }
      }
      float4v acc = ac0 + ac1;
      int col = lane & 15;
      int row0 = wv * 16 + ((lane >> 4) << 2);
      if (col < 4) {
#pragma unroll
        for (int reg = 0; reg < 4; ++reg) {
          int pr = row0 + reg;
          if (pr < 196) sm->u.p2.Y[pr * 5 + col] = acc[reg];
        }
      }
    }
    __syncthreads();
    // ---- ATA[r][s] = sum_p H[p][r] Y[p][s]; wave w handles (r,s)=w ----
    {
      int r = wv >> 2, s = wv & 3;
      float a = 0.f;
#pragma unroll
      for (int k4 = 0; k4 < 4; ++k4) {
        int p = lane + 64 * k4;
        if (p < 196) a += sm->u.p2.H[p * 5 + r] * sm->u.p2.Y[p * 5 + s];
      }
#pragma unroll
      for (int m = 32; m > 0; m >>= 1) a += __shfl_xor(a, m, 64);
      if (lane == 0) sm->Sm[SM_ATA + wv] = a;
    }
    __syncthreads();
    if (tid < 64) factor_update(sm, lane);
    __syncthreads();
  }

  // ================= Epilogue =================
  // y[i] = w2 . relu(w1 . (T0[i,:] H))  for i in 0..511; 2 threads per channel.
  {
    float hr[13];  // dense H (4p+r) spread over lanes, all waves load
#pragma unroll
    for (int k = 0; k < 13; ++k) {
      int d = 64 * k + lane;
      hr[k] = (d < 784) ? sm->u.p2.H[(d >> 2) * 5 + (d & 3)] : 0.f;
    }
    const int ch = tid & 511;
    const int half = tid >> 9;   // wave-uniform
    const float4* row = (const float4*)(xb + ch * 196);
    float a0 = 0.f, a1 = 0.f, a2 = 0.f, a3 = 0.f;
#define EPI_F4(F4)                                                     \
    {                                                                  \
      float4 v = row[(F4)];                                            \
      float vv[4] = {v.x, v.y, v.z, v.w};                              \
      _Pragma("unroll")                                                \
      for (int j = 0; j < 4; ++j) {                                    \
        int d = 16 * (F4) + 4 * j;                                     \
        a0 += vv[j] * rlane(hr[(d + 0) >> 6], (d + 0) & 63);           \
        a1 += vv[j] * rlane(hr[(d + 1) >> 6], (d + 1) & 63);           \
        a2 += vv[j] * rlane(hr[(d + 2) >> 6], (d + 2) & 63);           \
        a3 += vv[j] * rlane(hr[(d + 3) >> 6], (d + 3) & 63);           \
      }                                                                \
    }
    if (half == 0) {
#pragma unroll
      for (int f4 = 0; f4 < 25; ++f4) EPI_F4(f4)
    } else {
#pragma unroll
      for (int f4 = 25; f4 < 49; ++f4) EPI_F4(f4)
    }
#undef EPI_F4
    if (half) {
      float* pp = &sm->u.p2.g.f.part[ch * 5];
      pp[0] = a0; pp[1] = a1; pp[2] = a2; pp[3] = a3;
    }
    __syncthreads();
    if (tid < 512) {
      const float* pp = &sm->u.p2.g.f.part[tid * 5];
      a0 += pp[0]; a1 += pp[1]; a2 += pp[2]; a3 += pp[3];
      float y = 0.f;
#pragma unroll
      for (int s = 0; s < 4; ++s) {
        float pre = w1[s * 4 + 0] * a0 + w1[s * 4 + 1] * a1 + w1[s * 4 + 2] * a2
                  + w1[s * 4 + 3] * a3;
        y += w2[s] * fmaxf(pre, 0.f);
      }
      sm->u.p2.Y[tid] = y;
    }
  }
  __syncthreads();
  // z[u] = relu(sum_c y[c] fw1[u][c]) : 32 lanes per u, half-wave reduce
  {
    int u = tid >> 5, lc = tid & 31;
    float a = 0.f;
#pragma unroll
    for (int k = 0; k < 16; ++k) {
      int c = lc + 32 * k;
      a += sm->u.p2.Y[c] * fw1[u * 512 + c];
    }
    a += __shfl_xor(a, 1, 64);
    a += __shfl_xor(a, 2, 64);
    a += __shfl_xor(a, 4, 64);
    a += __shfl_xor(a, 8, 64);
    a += __shfl_xor(a, 16, 64);
    if (lc == 0) sm->u.p2.Y[512 + u] = fmaxf(a, 0.f);
  }
  __syncthreads();
  // gate[c] = sigmoid(sum_u z[u] fw2[c][u])
  if (tid < 512) {
    const float4* f2r = (const float4*)(fw2 + tid * 32);
    float za = 0.f;
#pragma unroll
    for (int u4 = 0; u4 < 8; ++u4) {
      float4 fv = f2r[u4];
      za += fv.x * sm->u.p2.Y[512 + u4 * 4 + 0];
      za += fv.y * sm->u.p2.Y[512 + u4 * 4 + 1];
      za += fv.z * sm->u.p2.Y[512 + u4 * 4 + 2];
      za += fv.w * sm->u.p2.Y[512 + u4 * 4 + 3];
    }
    float g = 1.f / (1.f + __expf(-za));
    sm->u.p2.Y[tid] = g;  // y dead -> reuse as gate
  }
  __syncthreads();
  // out = x * gate  (float4, coalesced; 49 float4 per channel)
  {
    const float4* xi = (const float4*)xb;
    float4* oo = (float4*)(out + (size_t)b * 100352);
#pragma unroll
    for (int t = 0; t < 25; ++t) {
      int v = tid + t * 1024;
      if (v < 25088) {
        float4 q = xi[v];
        float g = sm->u.p2.Y[v / 49];
        oo[v] = make_float4(q.x * g, q.y * g, q.z * g, q.w * g);
      }
    }
  }
}

extern "C" void kernel_launch(void* const* d_in, const int* in_sizes, int n_in,
                              void* d_out, int out_size, void* d_ws, size_t ws_size,
                              hipStream_t stream) {
  (void)in_sizes; (void)n_in; (void)d_ws; (void)ws_size; (void)out_size;
  const float* x   = (const float*)d_in[0];
  // d_in[1] = A0: unused (overwritten before first use in the reference)
  const float* B0  = (const float*)d_in[2];
  const float* C0  = (const float*)d_in[3];
  const float* w1  = (const float*)d_in[4];
  const float* w2  = (const float*)d_in[5];
  const float* fw1 = (const float*)d_in[6];
  const float* fw2 = (const float*)d_in[7];
  float* out = (float*)d_out;

  size_t shmem = sizeof(SMem);  // ~163 KB, fits gfx950's 160 KiB LDS
  hipFuncSetAttribute((const void*)dese_kernel,
                      hipFuncAttributeMaxDynamicSharedMemorySize, (int)shmem);
  hipLaunchKernelGGL(dese_kernel, dim3(256), dim3(1024), shmem, stream,
                     x, B0, C0, w1, w2, fw1, fw2, out);
}

// Round 2
// 370.323 us; speedup vs baseline: 1.2624x; 1.1393x over previous
//
#include <hip/hip_runtime.h>

// DeSELayer: per-sample CP-ALS(rank4, 20 it) -> rank_fc -> SE fc -> sigmoid gate.
// Gram-trick: iterations run on Gram = T0^T T0 (196x196).
// 1 workgroup (1024 thr) per sample; grid = 256 = #CUs.
// R3: phase-1 Gram via MFMA split-bf16.
// R4: phase-2 Y = Gram*H via MFMA (A-frags of Gram in registers per wave).
// R5: (a) phase-1 fragments built DIRECTLY from global (stage_f + transpose
//     pass removed); 2x4 register-blocked tile assignment (12 frag reads per
//     24 MFMAs vs 24 per 18) -> ~2x less LDS-pipe traffic.
//     (b) factor_update: 4x4 inverse as static closed-form adjugate from
//     readlane-broadcast G, Ginv kept in registers (no LDS G/COF/GINV/M, no
//     scratch from runtime-indexed arrays, 2 fences instead of ~15).

#define EPSV 1e-6f

#define SM_ATA  104   // 16 floats inside Sm[]

typedef __attribute__((ext_vector_type(8))) short short8;
typedef __attribute__((ext_vector_type(4))) float float4v;

struct SMem {
  union {
    struct {                      // ---- phase 1 ----
      short xhi[4 * 13 * 64 * 8]; // frag-order: [kstep s][tile T][lane][8 ch] bf16
      short xlo[4 * 13 * 64 * 8]; // 53,248 B each
    } p1;
    struct {                      // ---- phase 2 ----
      union {
        float gram[196 * 197];    // 154,448 B; dead after A-frag build
        struct {                  // live after A-frag build
          short fh[7 * 64 * 8];   // H B-fragments bf16 hi: [kb][lane][8]
          short fl[7 * 64 * 8];   // H B-fragments bf16 lo
          float part[512 * 5];    // epilogue partial sums (stride 5)
        } f;
      } g;
      float H[196 * 5];           // stride 5
      float Y[196 * 5];           // stride 5; epilogue: y[512] @0, z[32] @512
    } p2;
  } u;
  float B[56];                    // B[j][r] flat j*4+r
  float C[56];
  float Sm[120];                  // only SM_ATA window used now
};

__device__ __forceinline__ float rlane(float v, int l) {
  return __uint_as_float(__builtin_amdgcn_readlane(__float_as_uint(v), l));
}
__device__ __forceinline__ void fence_lds() { __threadfence_block(); }

// round-to-nearest-even fp32 -> bf16 (returned in low 16 bits)
__device__ __forceinline__ unsigned bf16rne(float f) {
  unsigned u = __float_as_uint(f);
  return (u + 0x7FFFu + ((u >> 16) & 1u)) >> 16;
}

// (V^T V)[r][s] per lane (meaningful pattern repeats across lanes); V = 14x4 flat
__device__ __forceinline__ float gram16(const float* V, int l) {
  int r = (l >> 2) & 3, s = l & 3;
  float a = 0.f;
#pragma unroll
  for (int j = 0; j < 14; ++j) a += V[j * 4 + r] * V[j * 4 + s];
  return a;
}

// 2-bit select of 4 candidates (static candidates, runtime k) -> 3 cndmask
__device__ __forceinline__ float sel4(float a, float b, float c, float d, int k) {
  float x = (k & 1) ? b : a;
  float y = (k & 1) ? d : c;
  return (k & 2) ? y : x;
}

// All lanes of wave 0: myG at lane t=i*4+j holds G[i][j] (valid t<16).
// Produces full inverse in gv[16] (row-major), all indices STATIC -> registers.
__device__ __forceinline__ void ginv_lanes(float myG, float gv[16]) {
  const float a00 = rlane(myG, 0),  a01 = rlane(myG, 1),  a02 = rlane(myG, 2),  a03 = rlane(myG, 3);
  const float a10 = rlane(myG, 4),  a11 = rlane(myG, 5),  a12 = rlane(myG, 6),  a13 = rlane(myG, 7);
  const float a20 = rlane(myG, 8),  a21 = rlane(myG, 9),  a22 = rlane(myG, 10), a23 = rlane(myG, 11);
  const float a30 = rlane(myG, 12), a31 = rlane(myG, 13), a32 = rlane(myG, 14), a33 = rlane(myG, 15);
  const float s0 = a00*a11 - a10*a01, s1 = a00*a12 - a10*a02, s2 = a00*a13 - a10*a03;
  const float s3 = a01*a12 - a11*a02, s4 = a01*a13 - a11*a03, s5 = a02*a13 - a12*a03;
  const float c5 = a22*a33 - a32*a23, c4 = a21*a33 - a31*a23, c3 = a21*a32 - a31*a22;
  const float c2 = a20*a33 - a30*a23, c1 = a20*a32 - a30*a22, c0 = a20*a31 - a30*a21;
  const float det = s0*c5 - s1*c4 + s2*c3 + s3*c2 - s4*c1 + s5*c0;
  const float rd = 1.0f / det;
  gv[0]  = ( a11*c5 - a12*c4 + a13*c3) * rd;
  gv[1]  = (-a01*c5 + a02*c4 - a03*c3) * rd;
  gv[2]  = ( a31*s5 - a32*s4 + a33*s3) * rd;
  gv[3]  = (-a21*s5 + a22*s4 - a23*s3) * rd;
  gv[4]  = (-a10*c5 + a12*c2 - a13*c1) * rd;
  gv[5]  = ( a00*c5 - a02*c2 + a03*c1) * rd;
  gv[6]  = (-a30*s5 + a32*s2 - a33*s1) * rd;
  gv[7]  = ( a20*s5 - a22*s2 + a23*s1) * rd;
  gv[8]  = ( a10*c4 - a11*c2 + a13*c0) * rd;
  gv[9]  = (-a00*c4 + a01*c2 - a03*c0) * rd;
  gv[10] = ( a30*s4 - a31*s2 + a33*s0) * rd;
  gv[11] = (-a20*s4 + a21*s2 - a23*s0) * rd;
  gv[12] = (-a10*c3 + a11*c1 - a12*c0) * rd;
  gv[13] = ( a00*c3 - a01*c1 + a02*c0) * rd;
  gv[14] = (-a30*s3 + a31*s1 - a32*s0) * rd;
  gv[15] = ( a20*s3 - a21*s1 + a22*s0) * rd;
}

// wave 0: H[p][r] = sum_s B[j][s]C[k][s] * Ginv[s][r] (Ginv in regs, static idx).
// Writes fp32 H (stride 5) AND scatters bf16 hi/lo into B-fragment arrays.
__device__ __forceinline__ void computeH_scatter(SMem* sm, int l, const float gv[16]) {
#pragma unroll
  for (int k4 = 0; k4 < 4; ++k4) {
    int p = l + 64 * k4;
    if (p < 196) {
      int j = p / 14, kk = p - j * 14;
      float kr[4];
#pragma unroll
      for (int s = 0; s < 4; ++s) kr[s] = sm->B[j * 4 + s] * sm->C[kk * 4 + s];
      int kb = p >> 5, ii = p & 7, lrow = ((p >> 3) & 3) * 16;
#pragma unroll
      for (int r = 0; r < 4; ++r) {
        float h = kr[0] * gv[0 + r] + kr[1] * gv[4 + r]
                + kr[2] * gv[8 + r] + kr[3] * gv[12 + r];
        sm->u.p2.H[p * 5 + r] = h;
        unsigned hh = bf16rne(h);
        float hf = __uint_as_float(hh << 16);
        unsigned ll = bf16rne(h - hf);
        int fi = (kb * 64 + lrow + r) * 8 + ii;
        sm->u.p2.g.f.fh[fi] = (short)hh;
        sm->u.p2.g.f.fl[fi] = (short)ll;
      }
    }
  }
}

__device__ __forceinline__ void initial_H(SMem* sm, int l) {
  float btb = gram16(sm->B, l);
  float ctc = gram16(sm->C, l);
  float dgl = ((l >> 2) == (l & 3)) ? EPSV : 0.f;
  float myG = btb * ctc + dgl;
  float gv[16];
  ginv_lanes(myG, gv);
  computeH_scatter(sm, l, gv);
}

// wave 0 (all 64 lanes): ATA in Sm[ATA], Y current. Updates B, C, then next H.
__device__ __forceinline__ void factor_update(SMem* sm, int l) {
  const int jj = l >> 2, r = l & 3;
  const float dgl = ((l >> 2) == (l & 3)) ? EPSV : 0.f;
  float gv[16];
  float btb_new;
  // --- B update: G_B = ATA o CtC(old) + eps ---
  {
    float ctc_old = gram16(sm->C, l);
    float ata = sm->Sm[SM_ATA + (l & 15)];
    ginv_lanes(ata * ctc_old + dgl, gv);
    float m = 0.f;
    if (l < 56) {
#pragma unroll
      for (int k = 0; k < 14; ++k) m += sm->u.p2.Y[(jj * 14 + k) * 5 + r] * sm->C[k * 4 + r];
    }
    float bn = 0.f;
#pragma unroll
    for (int e = 0; e < 4; ++e) {
      float me = e ? __shfl_xor(m, e, 64) : m;           // M[jj][r^e]
      float coef = sel4(gv[((0 ^ e) << 2) + 0], gv[((1 ^ e) << 2) + 1],
                        gv[((2 ^ e) << 2) + 2], gv[((3 ^ e) << 2) + 3], r); // Ginv[r^e][r]
      bn += me * coef;
    }
    if (l < 56) sm->B[l] = bn;
  }
  fence_lds();
  // --- C update: G_C = ATA o BtB(new) + eps ---
  {
    btb_new = gram16(sm->B, l);
    float ata = sm->Sm[SM_ATA + (l & 15)];
    ginv_lanes(ata * btb_new + dgl, gv);
    float m = 0.f;
    if (l < 56) {
#pragma unroll
      for (int j = 0; j < 14; ++j) m += sm->u.p2.Y[(j * 14 + jj) * 5 + r] * sm->B[j * 4 + r];
    }
    float cn = 0.f;
#pragma unroll
    for (int e = 0; e < 4; ++e) {
      float me = e ? __shfl_xor(m, e, 64) : m;
      float coef = sel4(gv[((0 ^ e) << 2) + 0], gv[((1 ^ e) << 2) + 1],
                        gv[((2 ^ e) << 2) + 2], gv[((3 ^ e) << 2) + 3], r);
      cn += me * coef;
    }
    if (l < 56) sm->C[l] = cn;
  }
  fence_lds();
  // --- next-iteration H: G_A = BtB(new) o CtC(new) + eps ---
  {
    float ctc_new = gram16(sm->C, l);
    ginv_lanes(btb_new * ctc_new + dgl, gv);
    computeH_scatter(sm, l, gv);
  }
}

extern "C" __global__ void __launch_bounds__(1024, 4)
dese_kernel(const float* __restrict__ x, const float* __restrict__ B0,
            const float* __restrict__ C0, const float* __restrict__ w1,
            const float* __restrict__ w2, const float* __restrict__ fw1,
            const float* __restrict__ fw2, float* __restrict__ out) {
  extern __shared__ char smraw[];
  SMem* sm = (SMem*)smraw;
  const int tid = threadIdx.x;
  const int b = blockIdx.x;
  const int wv = tid >> 6;
  const int lane = tid & 63;
  const float* xb = x + (size_t)b * 100352;

  // load per-sample B0, C0 (A0 is dead: first ALS step overwrites A)
  if (tid < 56) sm->B[tid] = B0[b * 56 + tid];
  if (tid >= 64 && tid < 120) sm->C[tid - 64] = C0[b * 56 + (tid - 64)];

  // ================= Phase 1: Gram = X X^T via MFMA split-bf16 =================
  // X = T0^T (196 spatial x 512 ch), padded to 208 rows (13 tiles of 16).
  // 2x4 register-blocked: wave -> row-pair I0,I0+1 x col-quad J0..J0+3.
  // Block table over the 13x13 upper triangle: per row-pair R, ceil((13-2R)/4)
  // col-chunks -> exactly 16 blocks. acc += hi*hi + hi*lo + lo*hi (fp32).
  {
    const int R = (wv >= 4) + (wv >= 7) + (wv >= 10) + (wv >= 12) + (wv >= 14) + (wv >= 15);
    const int base = (R == 0) ? 0 : (R == 1) ? 4 : (R == 2) ? 7 : (R == 3) ? 10
                   : (R == 4) ? 12 : (R == 5) ? 14 : 15;
    const int I0 = 2 * R;
    const int J0 = I0 + 4 * (wv - base);
    const int IC1 = (I0 + 1 <= 12) ? I0 + 1 : 12;   // clamped read index
    const bool iok1 = (I0 + 1 <= 12);

    float4v acc0[4], acc1[4];
#pragma unroll
    for (int i = 0; i < 4; ++i) {
      acc0[i] = (float4v){0.f, 0.f, 0.f, 0.f};
      acc1[i] = (float4v){0.f, 0.f, 0.f, 0.f};
    }

    for (int chunk = 0; chunk < 4; ++chunk) {
      __syncthreads();  // prev chunk's MFMA frag reads done
      // ---- build bf16 hi/lo fragments directly from global ----
      // unit u = (kstep s, ptile pt); 52 units over 16 waves.
#pragma unroll
      for (int t = 0; t < 4; ++t) {
        int u = wv + 16 * t;
        if (u < 52) {
          int s = u / 13, pt = u - s * 13;          // wave-uniform
          int p = pt * 16 + (lane & 15);
          int chb = chunk * 128 + s * 32 + (lane >> 4) * 8;
          unsigned hp[4], lp[4];
#pragma unroll
          for (int ii = 0; ii < 8; ++ii) {
            float v = 0.f;
            if (p < 196) v = xb[(size_t)(chb + ii) * 196 + p];
            unsigned h = bf16rne(v);
            float hf = __uint_as_float(h << 16);
            unsigned lo2 = bf16rne(v - hf);
            if (ii & 1) { hp[ii >> 1] |= (h << 16); lp[ii >> 1] |= (lo2 << 16); }
            else        { hp[ii >> 1] = h;          lp[ii >> 1] = lo2; }
          }
          int fidx = (s * 13 + pt) * 64 + lane;
          *(uint4*)&sm->u.p1.xhi[fidx * 8] = make_uint4(hp[0], hp[1], hp[2], hp[3]);
          *(uint4*)&sm->u.p1.xlo[fidx * 8] = make_uint4(lp[0], lp[1], lp[2], lp[3]);
        }
      }
      __syncthreads();  // fragments ready
      // ---- MFMA: 4 ksteps x (2 row-frags + 4 col-frags -> 8 tiles) ----
#pragma unroll
      for (int s = 0; s < 4; ++s) {
        const short8 aH0 = *(const short8*)&sm->u.p1.xhi[((s * 13 + I0)  * 64 + lane) * 8];
        const short8 aL0 = *(const short8*)&sm->u.p1.xlo[((s * 13 + I0)  * 64 + lane) * 8];
        const short8 aH1 = *(const short8*)&sm->u.p1.xhi[((s * 13 + IC1) * 64 + lane) * 8];
        const short8 aL1 = *(const short8*)&sm->u.p1.xlo[((s * 13 + IC1) * 64 + lane) * 8];
#pragma unroll
        for (int j = 0; j < 4; ++j) {
          const int J = J0 + j;
          if (J <= 12) {                            // wave-uniform
            const short8 bH = *(const short8*)&sm->u.p1.xhi[((s * 13 + J) * 64 + lane) * 8];
            const short8 bL = *(const short8*)&sm->u.p1.xlo[((s * 13 + J) * 64 + lane) * 8];
            acc0[j] = __builtin_amdgcn_mfma_f32_16x16x32_bf16(aH0, bH, acc0[j], 0, 0, 0);
            acc0[j] = __builtin_amdgcn_mfma_f32_16x16x32_bf16(aH0, bL, acc0[j], 0, 0, 0);
            acc0[j] = __builtin_amdgcn_mfma_f32_16x16x32_bf16(aL0, bH, acc0[j], 0, 0, 0);
            if (iok1 && I0 + 1 <= J) {              // wave-uniform
              acc1[j] = __builtin_amdgcn_mfma_f32_16x16x32_bf16(aH1, bH, acc1[j], 0, 0, 0);
              acc1[j] = __builtin_amdgcn_mfma_f32_16x16x32_bf16(aH1, bL, acc1[j], 0, 0, 0);
              acc1[j] = __builtin_amdgcn_mfma_f32_16x16x32_bf16(aL1, bH, acc1[j], 0, 0, 0);
            }
          }
        }
      }
    }
    __syncthreads();  // all MFMA frag reads done; p1 region now dead
    // ---- write acc -> gram (C/D layout: col=lane&15, row=quad*4+reg) + mirror ----
    {
      int col = lane & 15, quad = lane >> 4;
#define WRITE_TILE(ACC, I)                                          \
      {                                                             \
        int pc = (J0 + j) * 16 + col;                               \
        _Pragma("unroll")                                           \
        for (int reg = 0; reg < 4; ++reg) {                         \
          int pr = (I) * 16 + quad * 4 + reg;                       \
          if (pr < 196 && pc < 196) {                               \
            float v = ACC[j][reg];                                  \
            sm->u.p2.g.gram[pr * 197 + pc] = v;                     \
            sm->u.p2.g.gram[pc * 197 + pr] = v;                     \
          }                                                         \
        }                                                           \
      }
#pragma unroll
      for (int j = 0; j < 4; ++j) {
        const int J = J0 + j;
        if (J <= 12) {
          WRITE_TILE(acc0, I0)
          if (iok1 && I0 + 1 <= J) WRITE_TILE(acc1, I0 + 1)
        }
      }
#undef WRITE_TILE
    }
  }
  __syncthreads();

  // ============ A-fragment build: wave J holds Gram row-block J in regs ========
  // A-frag (16x16x32): lane l, elem i -> A[m=l&15, k=(l>>4)*8+i] = G[J*16+m, kb*32+k].
  short8 afh[7], afl[7];
  if (wv < 13) {
    const int m = wv * 16 + (lane & 15);
    const int mok = (m < 196);
    const int kq = (lane >> 4) * 8;
#pragma unroll
    for (int kb = 0; kb < 7; ++kb) {
#pragma unroll
      for (int i = 0; i < 8; ++i) {
        int k = kb * 32 + kq + i;
        float v = (mok && k < 196) ? sm->u.p2.g.gram[m * 197 + k] : 0.f;
        unsigned h = bf16rne(v);
        float hf = __uint_as_float(h << 16);
        unsigned lo = bf16rne(v - hf);
        afh[kb][i] = (short)h;
        afl[kb][i] = (short)lo;
      }
    }
  }
  __syncthreads();  // gram fully consumed; its region may now be reused
  // zero-fill H B-fragment arrays once (pads stay zero forever)
  {
    unsigned* z = (unsigned*)sm->u.p2.g.f.fh;  // fh+fl contiguous: 3584 u32
#pragma unroll
    for (int t = 0; t < 4; ++t) {
      int idx = tid + 1024 * t;
      if (idx < 3584) z[idx] = 0u;
    }
  }
  __syncthreads();

  // ================= Phase 2: 19 ALS iteration bodies on Gram =================
  if (tid < 64) initial_H(sm, lane);
  __syncthreads();

  for (int it = 0; it < 19; ++it) {
    // ---- Y[p][r] = Gram*H via MFMA: wave J -> Y rows J*16..+15, no atomics ----
    if (wv < 13) {
      float4v ac0 = {0.f, 0.f, 0.f, 0.f}, ac1 = {0.f, 0.f, 0.f, 0.f};
#pragma unroll
      for (int kb = 0; kb < 7; ++kb) {
        const short8 bh = *(const short8*)&sm->u.p2.g.f.fh[(kb * 64 + lane) * 8];
        const short8 bl = *(const short8*)&sm->u.p2.g.f.fl[(kb * 64 + lane) * 8];
        if (kb & 1) {
          ac1 = __builtin_amdgcn_mfma_f32_16x16x32_bf16(afh[kb], bh, ac1, 0, 0, 0);
          ac1 = __builtin_amdgcn_mfma_f32_16x16x32_bf16(afh[kb], bl, ac1, 0, 0, 0);
          ac1 = __builtin_amdgcn_mfma_f32_16x16x32_bf16(afl[kb], bh, ac1, 0, 0, 0);
        } else {
          ac0 = __builtin_amdgcn_mfma_f32_16x16x32_bf16(afh[kb], bh, ac0, 0, 0, 0);
          ac0 = __builtin_amdgcn_mfma_f32_16x16x32_bf16(afh[kb], bl, ac0, 0, 0, 0);
          ac0 = __builtin_amdgcn_mfma_f32_16x16x32_bf16(afl[kb], bh, ac0, 0, 0, 0);
        }
      }
      float4v acc = ac0 + ac1;
      int col = lane & 15;
      int row0 = wv * 16 + ((lane >> 4) << 2);
      if (col < 4) {
#pragma unroll
        for (int reg = 0; reg < 4; ++reg) {
          int pr = row0 + reg;
          if (pr < 196) sm->u.p2.Y[pr * 5 + col] = acc[reg];
        }
      }
    }
    __syncthreads();
    // ---- ATA[r][s] = sum_p H[p][r] Y[p][s]; wave w handles (r,s)=w ----
    {
      int r = wv >> 2, s = wv & 3;
      float a = 0.f;
#pragma unroll
      for (int k4 = 0; k4 < 4; ++k4) {
        int p = lane + 64 * k4;
        if (p < 196) a += sm->u.p2.H[p * 5 + r] * sm->u.p2.Y[p * 5 + s];
      }
#pragma unroll
      for (int m = 32; m > 0; m >>= 1) a += __shfl_xor(a, m, 64);
      if (lane == 0) sm->Sm[SM_ATA + wv] = a;
    }
    __syncthreads();
    if (tid < 64) factor_update(sm, lane);
    __syncthreads();
  }

  // ================= Epilogue =================
  // y[i] = w2 . relu(w1 . (T0[i,:] H))  for i in 0..511; 2 threads per channel.
  {
    float hr[13];  // dense H (4p+r) spread over lanes, all waves load
#pragma unroll
    for (int k = 0; k < 13; ++k) {
      int d = 64 * k + lane;
      hr[k] = (d < 784) ? sm->u.p2.H[(d >> 2) * 5 + (d & 3)] : 0.f;
    }
    const int ch = tid & 511;
    const int half = tid >> 9;   // wave-uniform
    const float4* row = (const float4*)(xb + ch * 196);
    float a0 = 0.f, a1 = 0.f, a2 = 0.f, a3 = 0.f;
#define EPI_F4(F4)                                                     \
    {                                                                  \
      float4 v = row[(F4)];                                            \
      float vv[4] = {v.x, v.y, v.z, v.w};                              \
      _Pragma("unroll")                                                \
      for (int j = 0; j < 4; ++j) {                                    \
        int d = 16 * (F4) + 4 * j;                                     \
        a0 += vv[j] * rlane(hr[(d + 0) >> 6], (d + 0) & 63);           \
        a1 += vv[j] * rlane(hr[(d + 1) >> 6], (d + 1) & 63);           \
        a2 += vv[j] * rlane(hr[(d + 2) >> 6], (d + 2) & 63);           \
        a3 += vv[j] * rlane(hr[(d + 3) >> 6], (d + 3) & 63);           \
      }                                                                \
    }
    if (half == 0) {
#pragma unroll
      for (int f4 = 0; f4 < 25; ++f4) EPI_F4(f4)
    } else {
#pragma unroll
      for (int f4 = 25; f4 < 49; ++f4) EPI_F4(f4)
    }
#undef EPI_F4
    if (half) {
      float* pp = &sm->u.p2.g.f.part[ch * 5];
      pp[0] = a0; pp[1] = a1; pp[2] = a2; pp[3] = a3;
    }
    __syncthreads();
    if (tid < 512) {
      const float* pp = &sm->u.p2.g.f.part[tid * 5];
      a0 += pp[0]; a1 += pp[1]; a2 += pp[2]; a3 += pp[3];
      float y = 0.f;
#pragma unroll
      for (int s = 0; s < 4; ++s) {
        float pre = w1[s * 4 + 0] * a0 + w1[s * 4 + 1] * a1 + w1[s * 4 + 2] * a2
                  + w1[s * 4 + 3] * a3;
        y += w2[s] * fmaxf(pre, 0.f);
      }
      sm->u.p2.Y[tid] = y;
    }
  }
  __syncthreads();
  // z[u] = relu(sum_c y[c] fw1[u][c]) : 32 lanes per u, half-wave reduce
  {
    int u = tid >> 5, lc = tid & 31;
    float a = 0.f;
#pragma unroll
    for (int k = 0; k < 16; ++k) {
      int c = lc + 32 * k;
      a += sm->u.p2.Y[c] * fw1[u * 512 + c];
    }
    a += __shfl_xor(a, 1, 64);
    a += __shfl_xor(a, 2, 64);
    a += __shfl_xor(a, 4, 64);
    a += __shfl_xor(a, 8, 64);
    a += __shfl_xor(a, 16, 64);
    if (lc == 0) sm->u.p2.Y[512 + u] = fmaxf(a, 0.f);
  }
  __syncthreads();
  // gate[c] = sigmoid(sum_u z[u] fw2[c][u])
  if (tid < 512) {
    const float4* f2r = (const float4*)(fw2 + tid * 32);
    float za = 0.f;
#pragma unroll
    for (int u4 = 0; u4 < 8; ++u4) {
      float4 fv = f2r[u4];
      za += fv.x * sm->u.p2.Y[512 + u4 * 4 + 0];
      za += fv.y * sm->u.p2.Y[512 + u4 * 4 + 1];
      za += fv.z * sm->u.p2.Y[512 + u4 * 4 + 2];
      za += fv.w * sm->u.p2.Y[512 + u4 * 4 + 3];
    }
    float g = 1.f / (1.f + __expf(-za));
    sm->u.p2.Y[tid] = g;  // y dead -> reuse as gate
  }
  __syncthreads();
  // out = x * gate  (float4, coalesced; 49 float4 per channel)
  {
    const float4* xi = (const float4*)xb;
    float4* oo = (float4*)(out + (size_t)b * 100352);
#pragma unroll
    for (int t = 0; t < 25; ++t) {
      int v = tid + t * 1024;
      if (v < 25088) {
        float4 q = xi[v];
        float g = sm->u.p2.Y[v / 49];
        oo[v] = make_float4(q.x * g, q.y * g, q.z * g, q.w * g);
      }
    }
  }
}

extern "C" void kernel_launch(void* const* d_in, const int* in_sizes, int n_in,
                              void* d_out, int out_size, void* d_ws, size_t ws_size,
                              hipStream_t stream) {
  (void)in_sizes; (void)n_in; (void)d_ws; (void)ws_size; (void)out_size;
  const float* x   = (const float*)d_in[0];
  // d_in[1] = A0: unused (overwritten before first use in the reference)
  const float* B0  = (const float*)d_in[2];
  const float* C0  = (const float*)d_in[3];
  const float* w1  = (const float*)d_in[4];
  const float* w2  = (const float*)d_in[5];
  const float* fw1 = (const float*)d_in[6];
  const float* fw2 = (const float*)d_in[7];
  float* out = (float*)d_out;

  size_t shmem = sizeof(SMem);  // ~163 KB, fits gfx950's 160 KiB LDS
  hipFuncSetAttribute((const void*)dese_kernel,
                      hipFuncAttributeMaxDynamicSharedMemorySize, (int)shmem);
  hipLaunchKernelGGL(dese_kernel, dim3(256), dim3(1024), shmem, stream,
                     x, B0, C0, w1, w2, fw1, fw2, out);
}

// Round 3
// 364.253 us; speedup vs baseline: 1.2834x; 1.0167x over previous
//
#include <hip/hip_runtime.h>

// DeSELayer: per-sample CP-ALS(rank4, 20 it) -> rank_fc -> SE fc -> sigmoid gate.
// Gram-trick: iterations run on Gram = T0^T T0 (196x196).
// 1 workgroup (1024 thr) per sample; grid = 256 = #CUs.
// R3: phase-1 Gram via MFMA split-bf16.
// R4: phase-2 Y = Gram*H via MFMA (A-frags of Gram in registers per wave).
// R5: phase-1 frags direct from global; 2x4 register-blocked tiles;
//     factor_update with closed-form reg inverse (no scratch, 2 fences).
// R6: (a) ATA fused into Y phase (per-wave reg partials + LDS atomicAdd),
//     removing the ATA phase and one barrier per iteration (3->2).
//     (b) gram16(C_old) hoisted to wave 13 during Y phase.
//     (c) phase-1 async-stage: chunk c+1's global loads issued into registers
//     before chunk c's MFMA (latency hidden under compute).
//     (d) dead fh/fl scatter skipped on last iteration.

#define EPSV 1e-6f

#define SM_CTC  32    // 16 floats: wave-13-precomputed CtC_old pattern
#define SM_ATA  104   // 16 floats

typedef __attribute__((ext_vector_type(8))) short short8;
typedef __attribute__((ext_vector_type(4))) float float4v;

struct SMem {
  union {
    struct {                      // ---- phase 1 ----
      short xhi[4 * 13 * 64 * 8]; // frag-order: [kstep s][tile T][lane][8 ch] bf16
      short xlo[4 * 13 * 64 * 8]; // 53,248 B each
    } p1;
    struct {                      // ---- phase 2 ----
      union {
        float gram[196 * 197];    // 154,448 B; dead after A-frag build
        struct {                  // live after A-frag build
          short fh[7 * 64 * 8];   // H B-fragments bf16 hi: [kb][lane][8]
          short fl[7 * 64 * 8];   // H B-fragments bf16 lo
          float part[512 * 5];    // epilogue partial sums (stride 5)
        } f;
      } g;
      float H[196 * 5];           // stride 5
      float Y[196 * 5];           // stride 5; epilogue: y[512] @0, z[32] @512
    } p2;
  } u;
  float B[56];                    // B[j][r] flat j*4+r
  float C[56];
  float Sm[120];                  // SM_CTC, SM_ATA windows
};

__device__ __forceinline__ float rlane(float v, int l) {
  return __uint_as_float(__builtin_amdgcn_readlane(__float_as_uint(v), l));
}
__device__ __forceinline__ void fence_lds() { __threadfence_block(); }

// round-to-nearest-even fp32 -> bf16 (returned in low 16 bits)
__device__ __forceinline__ unsigned bf16rne(float f) {
  unsigned u = __float_as_uint(f);
  return (u + 0x7FFFu + ((u >> 16) & 1u)) >> 16;
}

// (V^T V)[r][s] per lane (pattern repeats across lanes); V = 14x4 flat
__device__ __forceinline__ float gram16(const float* V, int l) {
  int r = (l >> 2) & 3, s = l & 3;
  float a = 0.f;
#pragma unroll
  for (int j = 0; j < 14; ++j) a += V[j * 4 + r] * V[j * 4 + s];
  return a;
}

// 2-bit select of 4 candidates (static candidates, runtime k) -> 3 cndmask
__device__ __forceinline__ float sel4(float a, float b, float c, float d, int k) {
  float x = (k & 1) ? b : a;
  float y = (k & 1) ? d : c;
  return (k & 2) ? y : x;
}

// All lanes of wave 0: myG at lane t=i*4+j holds G[i][j] (valid t<16).
// Produces full inverse in gv[16] (row-major), all indices STATIC -> registers.
__device__ __forceinline__ void ginv_lanes(float myG, float gv[16]) {
  const float a00 = rlane(myG, 0),  a01 = rlane(myG, 1),  a02 = rlane(myG, 2),  a03 = rlane(myG, 3);
  const float a10 = rlane(myG, 4),  a11 = rlane(myG, 5),  a12 = rlane(myG, 6),  a13 = rlane(myG, 7);
  const float a20 = rlane(myG, 8),  a21 = rlane(myG, 9),  a22 = rlane(myG, 10), a23 = rlane(myG, 11);
  const float a30 = rlane(myG, 12), a31 = rlane(myG, 13), a32 = rlane(myG, 14), a33 = rlane(myG, 15);
  const float s0 = a00*a11 - a10*a01, s1 = a00*a12 - a10*a02, s2 = a00*a13 - a10*a03;
  const float s3 = a01*a12 - a11*a02, s4 = a01*a13 - a11*a03, s5 = a02*a13 - a12*a03;
  const float c5 = a22*a33 - a32*a23, c4 = a21*a33 - a31*a23, c3 = a21*a32 - a31*a22;
  const float c2 = a20*a33 - a30*a23, c1 = a20*a32 - a30*a22, c0 = a20*a31 - a30*a21;
  const float det = s0*c5 - s1*c4 + s2*c3 + s3*c2 - s4*c1 + s5*c0;
  const float rd = 1.0f / det;
  gv[0]  = ( a11*c5 - a12*c4 + a13*c3) * rd;
  gv[1]  = (-a01*c5 + a02*c4 - a03*c3) * rd;
  gv[2]  = ( a31*s5 - a32*s4 + a33*s3) * rd;
  gv[3]  = (-a21*s5 + a22*s4 - a23*s3) * rd;
  gv[4]  = (-a10*c5 + a12*c2 - a13*c1) * rd;
  gv[5]  = ( a00*c5 - a02*c2 + a03*c1) * rd;
  gv[6]  = (-a30*s5 + a32*s2 - a33*s1) * rd;
  gv[7]  = ( a20*s5 - a22*s2 + a23*s1) * rd;
  gv[8]  = ( a10*c4 - a11*c2 + a13*c0) * rd;
  gv[9]  = (-a00*c4 + a01*c2 - a03*c0) * rd;
  gv[10] = ( a30*s4 - a31*s2 + a33*s0) * rd;
  gv[11] = (-a20*s4 + a21*s2 - a23*s0) * rd;
  gv[12] = (-a10*c3 + a11*c1 - a12*c0) * rd;
  gv[13] = ( a00*c3 - a01*c1 + a02*c0) * rd;
  gv[14] = (-a30*s3 + a31*s1 - a32*s0) * rd;
  gv[15] = ( a20*s3 - a21*s1 + a22*s0) * rd;
}

// wave 0: H[p][r] = sum_s B[j][s]C[k][s] * Ginv[s][r] (Ginv in regs, static idx).
// Writes fp32 H (stride 5); if scatter, also bf16 hi/lo into B-fragment arrays.
__device__ __forceinline__ void computeH_scatter(SMem* sm, int l, const float gv[16],
                                                 bool scatter) {
#pragma unroll
  for (int k4 = 0; k4 < 4; ++k4) {
    int p = l + 64 * k4;
    if (p < 196) {
      int j = p / 14, kk = p - j * 14;
      float kr[4];
#pragma unroll
      for (int s = 0; s < 4; ++s) kr[s] = sm->B[j * 4 + s] * sm->C[kk * 4 + s];
      int kb = p >> 5, ii = p & 7, lrow = ((p >> 3) & 3) * 16;
#pragma unroll
      for (int r = 0; r < 4; ++r) {
        float h = kr[0] * gv[0 + r] + kr[1] * gv[4 + r]
                + kr[2] * gv[8 + r] + kr[3] * gv[12 + r];
        sm->u.p2.H[p * 5 + r] = h;
        if (scatter) {
          unsigned hh = bf16rne(h);
          float hf = __uint_as_float(hh << 16);
          unsigned ll = bf16rne(h - hf);
          int fi = (kb * 64 + lrow + r) * 8 + ii;
          sm->u.p2.g.f.fh[fi] = (short)hh;
          sm->u.p2.g.f.fl[fi] = (short)ll;
        }
      }
    }
  }
}

__device__ __forceinline__ void initial_H(SMem* sm, int l) {
  float btb = gram16(sm->B, l);
  float ctc = gram16(sm->C, l);
  float dgl = ((l >> 2) == (l & 3)) ? EPSV : 0.f;
  float myG = btb * ctc + dgl;
  float gv[16];
  ginv_lanes(myG, gv);
  if (l < 16) sm->Sm[SM_ATA + l] = 0.f;   // ready for first Y-phase atomics
  computeH_scatter(sm, l, gv, true);
}

// wave 0 (all 64 lanes): ATA in Sm[ATA] (zeroed here after read), CtC_old in
// Sm[CTC] (precomputed by wave 13). Updates B, C, then next H.
__device__ __forceinline__ void factor_update(SMem* sm, int l, bool last) {
  const int jj = l >> 2, r = l & 3;
  const float dgl = ((l >> 2) == (l & 3)) ? EPSV : 0.f;
  const float ata = sm->Sm[SM_ATA + (l & 15)];
  const float ctc_old = sm->Sm[SM_CTC + (l & 15)];
  if (l < 16) sm->Sm[SM_ATA + l] = 0.f;   // next iter's atomics start post-barrier
  float gv[16];
  float btb_new;
  // --- B update: G_B = ATA o CtC(old) + eps ---
  {
    ginv_lanes(ata * ctc_old + dgl, gv);
    float m = 0.f;
    if (l < 56) {
#pragma unroll
      for (int k = 0; k < 14; ++k) m += sm->u.p2.Y[(jj * 14 + k) * 5 + r] * sm->C[k * 4 + r];
    }
    float bn = 0.f;
#pragma unroll
    for (int e = 0; e < 4; ++e) {
      float me = e ? __shfl_xor(m, e, 64) : m;           // M[jj][r^e]
      float coef = sel4(gv[((0 ^ e) << 2) + 0], gv[((1 ^ e) << 2) + 1],
                        gv[((2 ^ e) << 2) + 2], gv[((3 ^ e) << 2) + 3], r); // Ginv[r^e][r]
      bn += me * coef;
    }
    if (l < 56) sm->B[l] = bn;
  }
  fence_lds();
  // --- C update: G_C = ATA o BtB(new) + eps ---
  {
    btb_new = gram16(sm->B, l);
    ginv_lanes(ata * btb_new + dgl, gv);
    float m = 0.f;
    if (l < 56) {
#pragma unroll
      for (int j = 0; j < 14; ++j) m += sm->u.p2.Y[(j * 14 + jj) * 5 + r] * sm->B[j * 4 + r];
    }
    float cn = 0.f;
#pragma unroll
    for (int e = 0; e < 4; ++e) {
      float me = e ? __shfl_xor(m, e, 64) : m;
      float coef = sel4(gv[((0 ^ e) << 2) + 0], gv[((1 ^ e) << 2) + 1],
                        gv[((2 ^ e) << 2) + 2], gv[((3 ^ e) << 2) + 3], r);
      cn += me * coef;
    }
    if (l < 56) sm->C[l] = cn;
  }
  fence_lds();
  // --- next-iteration H: G_A = BtB(new) o CtC(new) + eps ---
  {
    float ctc_new = gram16(sm->C, l);
    ginv_lanes(btb_new * ctc_new + dgl, gv);
    computeH_scatter(sm, l, gv, !last);
  }
}

extern "C" __global__ void __launch_bounds__(1024, 4)
dese_kernel(const float* __restrict__ x, const float* __restrict__ B0,
            const float* __restrict__ C0, const float* __restrict__ w1,
            const float* __restrict__ w2, const float* __restrict__ fw1,
            const float* __restrict__ fw2, float* __restrict__ out) {
  extern __shared__ char smraw[];
  SMem* sm = (SMem*)smraw;
  const int tid = threadIdx.x;
  const int b = blockIdx.x;
  const int wv = tid >> 6;
  const int lane = tid & 63;
  const float* xb = x + (size_t)b * 100352;

  // load per-sample B0, C0 (A0 is dead: first ALS step overwrites A)
  if (tid < 56) sm->B[tid] = B0[b * 56 + tid];
  if (tid >= 64 && tid < 120) sm->C[tid - 64] = C0[b * 56 + (tid - 64)];

  // ================= Phase 1: Gram = X X^T via MFMA split-bf16 =================
  // X = T0^T (196 spatial x 512 ch), padded to 208 rows (13 tiles of 16).
  // 2x4 register-blocked: wave -> row-pair I0,I0+1 x col-quad J0..J0+3.
  // Async-stage: chunk c+1's global loads issued into registers before
  // chunk c's MFMA. acc += hi*hi + hi*lo + lo*hi (fp32).
  {
    const int R = (wv >= 4) + (wv >= 7) + (wv >= 10) + (wv >= 12) + (wv >= 14) + (wv >= 15);
    const int base = (R == 0) ? 0 : (R == 1) ? 4 : (R == 2) ? 7 : (R == 3) ? 10
                   : (R == 4) ? 12 : (R == 5) ? 14 : 15;
    const int I0 = 2 * R;
    const int J0 = I0 + 4 * (wv - base);
    const int IC1 = (I0 + 1 <= 12) ? I0 + 1 : 12;   // clamped read index
    const bool iok1 = (I0 + 1 <= 12);

    // per-t staging unit params (chunk-independent)
    int us_[4], upt_[4];
    bool uv_[4];
#pragma unroll
    for (int t = 0; t < 4; ++t) {
      int u = wv + 16 * t;
      uv_[t] = (u < 52);
      int s = uv_[t] ? (u / 13) : 0;
      us_[t] = s;
      upt_[t] = uv_[t] ? (u - s * 13) : 0;
    }
    const int pp_ = (lane & 15);
    const int co_ = (lane >> 4) * 8;

    float xr[4][8];
#define ISSUE_LOADS(CHUNK)                                                    \
    {                                                                         \
      _Pragma("unroll")                                                       \
      for (int t = 0; t < 4; ++t) {                                           \
        if (uv_[t]) {                                                         \
          int p = upt_[t] * 16 + pp_;                                         \
          int chb = (CHUNK) * 128 + us_[t] * 32 + co_;                        \
          _Pragma("unroll")                                                   \
          for (int ii = 0; ii < 8; ++ii)                                      \
            xr[t][ii] = (p < 196) ? xb[(size_t)(chb + ii) * 196 + p] : 0.f;   \
        }                                                                     \
      }                                                                       \
    }

    float4v acc0[4], acc1[4];
#pragma unroll
    for (int i = 0; i < 4; ++i) {
      acc0[i] = (float4v){0.f, 0.f, 0.f, 0.f};
      acc1[i] = (float4v){0.f, 0.f, 0.f, 0.f};
    }

    ISSUE_LOADS(0)
    for (int chunk = 0; chunk < 4; ++chunk) {
      __syncthreads();  // prev chunk's MFMA frag reads done
      // ---- convert staged registers -> bf16 hi/lo fragments in LDS ----
#pragma unroll
      for (int t = 0; t < 4; ++t) {
        if (uv_[t]) {
          unsigned hp[4], lp[4];
#pragma unroll
          for (int ii = 0; ii < 8; ++ii) {
            float v = xr[t][ii];
            unsigned h = bf16rne(v);
            float hf = __uint_as_float(h << 16);
            unsigned lo2 = bf16rne(v - hf);
            if (ii & 1) { hp[ii >> 1] |= (h << 16); lp[ii >> 1] |= (lo2 << 16); }
            else        { hp[ii >> 1] = h;          lp[ii >> 1] = lo2; }
          }
          int fidx = (us_[t] * 13 + upt_[t]) * 64 + lane;
          *(uint4*)&sm->u.p1.xhi[fidx * 8] = make_uint4(hp[0], hp[1], hp[2], hp[3]);
          *(uint4*)&sm->u.p1.xlo[fidx * 8] = make_uint4(lp[0], lp[1], lp[2], lp[3]);
        }
      }
      __syncthreads();  // fragments ready
      if (chunk < 3) ISSUE_LOADS(chunk + 1)   // hide HBM latency under MFMA
      // ---- MFMA: 4 ksteps x (2 row-frags + 4 col-frags -> 8 tiles) ----
#pragma unroll
      for (int s = 0; s < 4; ++s) {
        const short8 aH0 = *(const short8*)&sm->u.p1.xhi[((s * 13 + I0)  * 64 + lane) * 8];
        const short8 aL0 = *(const short8*)&sm->u.p1.xlo[((s * 13 + I0)  * 64 + lane) * 8];
        const short8 aH1 = *(const short8*)&sm->u.p1.xhi[((s * 13 + IC1) * 64 + lane) * 8];
        const short8 aL1 = *(const short8*)&sm->u.p1.xlo[((s * 13 + IC1) * 64 + lane) * 8];
#pragma unroll
        for (int j = 0; j < 4; ++j) {
          const int J = J0 + j;
          if (J <= 12) {                            // wave-uniform
            const short8 bH = *(const short8*)&sm->u.p1.xhi[((s * 13 + J) * 64 + lane) * 8];
            const short8 bL = *(const short8*)&sm->u.p1.xlo[((s * 13 + J) * 64 + lane) * 8];
            acc0[j] = __builtin_amdgcn_mfma_f32_16x16x32_bf16(aH0, bH, acc0[j], 0, 0, 0);
            acc0[j] = __builtin_amdgcn_mfma_f32_16x16x32_bf16(aH0, bL, acc0[j], 0, 0, 0);
            acc0[j] = __builtin_amdgcn_mfma_f32_16x16x32_bf16(aL0, bH, acc0[j], 0, 0, 0);
            if (iok1 && I0 + 1 <= J) {              // wave-uniform
              acc1[j] = __builtin_amdgcn_mfma_f32_16x16x32_bf16(aH1, bH, acc1[j], 0, 0, 0);
              acc1[j] = __builtin_amdgcn_mfma_f32_16x16x32_bf16(aH1, bL, acc1[j], 0, 0, 0);
              acc1[j] = __builtin_amdgcn_mfma_f32_16x16x32_bf16(aL1, bH, acc1[j], 0, 0, 0);
            }
          }
        }
      }
    }
#undef ISSUE_LOADS
    __syncthreads();  // all MFMA frag reads done; p1 region now dead
    // ---- write acc -> gram (C/D layout: col=lane&15, row=quad*4+reg) + mirror ----
    {
      int col = lane & 15, quad = lane >> 4;
#define WRITE_TILE(ACC, I)                                          \
      {                                                             \
        int pc = (J0 + j) * 16 + col;                               \
        _Pragma("unroll")                                           \
        for (int reg = 0; reg < 4; ++reg) {                         \
          int pr = (I) * 16 + quad * 4 + reg;                       \
          if (pr < 196 && pc < 196) {                               \
            float v = ACC[j][reg];                                  \
            sm->u.p2.g.gram[pr * 197 + pc] = v;                     \
            sm->u.p2.g.gram[pc * 197 + pr] = v;                     \
          }                                                         \
        }                                                           \
      }
#pragma unroll
      for (int j = 0; j < 4; ++j) {
        const int J = J0 + j;
        if (J <= 12) {
          WRITE_TILE(acc0, I0)
          if (iok1 && I0 + 1 <= J) WRITE_TILE(acc1, I0 + 1)
        }
      }
#undef WRITE_TILE
    }
  }
  __syncthreads();

  // ============ A-fragment build: wave J holds Gram row-block J in regs ========
  // A-frag (16x16x32): lane l, elem i -> A[m=l&15, k=(l>>4)*8+i] = G[J*16+m, kb*32+k].
  short8 afh[7], afl[7];
  if (wv < 13) {
    const int m = wv * 16 + (lane & 15);
    const int mok = (m < 196);
    const int kq = (lane >> 4) * 8;
#pragma unroll
    for (int kb = 0; kb < 7; ++kb) {
#pragma unroll
      for (int i = 0; i < 8; ++i) {
        int k = kb * 32 + kq + i;
        float v = (mok && k < 196) ? sm->u.p2.g.gram[m * 197 + k] : 0.f;
        unsigned h = bf16rne(v);
        float hf = __uint_as_float(h << 16);
        unsigned lo = bf16rne(v - hf);
        afh[kb][i] = (short)h;
        afl[kb][i] = (short)lo;
      }
    }
  }
  __syncthreads();  // gram fully consumed; its region may now be reused
  // zero-fill H B-fragment arrays once (pads stay zero forever)
  {
    unsigned* z = (unsigned*)sm->u.p2.g.f.fh;  // fh+fl contiguous: 3584 u32
#pragma unroll
    for (int t = 0; t < 4; ++t) {
      int idx = tid + 1024 * t;
      if (idx < 3584) z[idx] = 0u;
    }
  }
  __syncthreads();

  // ================= Phase 2: 19 ALS iteration bodies on Gram =================
  if (tid < 64) initial_H(sm, lane);
  __syncthreads();

  for (int it = 0; it < 19; ++it) {
    // ---- Y = Gram*H via MFMA + fused ATA partials; wave 13: CtC_old ----
    if (wv < 13) {
      float4v ac0 = {0.f, 0.f, 0.f, 0.f}, ac1 = {0.f, 0.f, 0.f, 0.f};
#pragma unroll
      for (int kb = 0; kb < 7; ++kb) {
        const short8 bh = *(const short8*)&sm->u.p2.g.f.fh[(kb * 64 + lane) * 8];
        const short8 bl = *(const short8*)&sm->u.p2.g.f.fl[(kb * 64 + lane) * 8];
        if (kb & 1) {
          ac1 = __builtin_amdgcn_mfma_f32_16x16x32_bf16(afh[kb], bh, ac1, 0, 0, 0);
          ac1 = __builtin_amdgcn_mfma_f32_16x16x32_bf16(afh[kb], bl, ac1, 0, 0, 0);
          ac1 = __builtin_amdgcn_mfma_f32_16x16x32_bf16(afl[kb], bh, ac1, 0, 0, 0);
        } else {
          ac0 = __builtin_amdgcn_mfma_f32_16x16x32_bf16(afh[kb], bh, ac0, 0, 0, 0);
          ac0 = __builtin_amdgcn_mfma_f32_16x16x32_bf16(afh[kb], bl, ac0, 0, 0, 0);
          ac0 = __builtin_amdgcn_mfma_f32_16x16x32_bf16(afl[kb], bh, ac0, 0, 0, 0);
        }
      }
      float4v acc = ac0 + ac1;
      const int col = lane & 15;
      const int quad = lane >> 4;
      const int row0 = wv * 16 + quad * 4;
      if (col < 4) {
        // Y stores
#pragma unroll
        for (int reg = 0; reg < 4; ++reg) {
          int pr = row0 + reg;
          if (pr < 196) sm->u.p2.Y[pr * 5 + col] = acc[reg];
        }
        // ATA partials: pa[r] = sum_reg H[row0+reg][r] * Y[row0+reg][col]
        float pa0 = 0.f, pa1 = 0.f, pa2 = 0.f, pa3 = 0.f;
#pragma unroll
        for (int reg = 0; reg < 4; ++reg) {
          int pr = row0 + reg;
          if (pr < 196) {
            float yv = acc[reg];
            pa0 += sm->u.p2.H[pr * 5 + 0] * yv;
            pa1 += sm->u.p2.H[pr * 5 + 1] * yv;
            pa2 += sm->u.p2.H[pr * 5 + 2] * yv;
            pa3 += sm->u.p2.H[pr * 5 + 3] * yv;
          }
        }
        // reduce across the 4 quads (same col)
        pa0 += __shfl_xor(pa0, 16, 64); pa0 += __shfl_xor(pa0, 32, 64);
        pa1 += __shfl_xor(pa1, 16, 64); pa1 += __shfl_xor(pa1, 32, 64);
        pa2 += __shfl_xor(pa2, 16, 64); pa2 += __shfl_xor(pa2, 32, 64);
        pa3 += __shfl_xor(pa3, 16, 64); pa3 += __shfl_xor(pa3, 32, 64);
        if (quad == 0) {
          atomicAdd(&sm->Sm[SM_ATA + 0 * 4 + col], pa0);
          atomicAdd(&sm->Sm[SM_ATA + 1 * 4 + col], pa1);
          atomicAdd(&sm->Sm[SM_ATA + 2 * 4 + col], pa2);
          atomicAdd(&sm->Sm[SM_ATA + 3 * 4 + col], pa3);
        }
      }
    } else if (wv == 13) {
      float ctc = gram16(sm->C, lane);       // C stable during Y phase
      if (lane < 16) sm->Sm[SM_CTC + lane] = ctc;
    }
    __syncthreads();
    if (tid < 64) factor_update(sm, lane, it == 18);
    __syncthreads();
  }

  // ================= Epilogue =================
  // y[i] = w2 . relu(w1 . (T0[i,:] H))  for i in 0..511; 2 threads per channel.
  {
    float hr[13];  // dense H (4p+r) spread over lanes, all waves load
#pragma unroll
    for (int k = 0; k < 13; ++k) {
      int d = 64 * k + lane;
      hr[k] = (d < 784) ? sm->u.p2.H[(d >> 2) * 5 + (d & 3)] : 0.f;
    }
    const int ch = tid & 511;
    const int half = tid >> 9;   // wave-uniform
    const float4* row = (const float4*)(xb + ch * 196);
    float a0 = 0.f, a1 = 0.f, a2 = 0.f, a3 = 0.f;
#define EPI_F4(F4)                                                     \
    {                                                                  \
      float4 v = row[(F4)];                                            \
      float vv[4] = {v.x, v.y, v.z, v.w};                              \
      _Pragma("unroll")                                                \
      for (int j = 0; j < 4; ++j) {                                    \
        int d = 16 * (F4) + 4 * j;                                     \
        a0 += vv[j] * rlane(hr[(d + 0) >> 6], (d + 0) & 63);           \
        a1 += vv[j] * rlane(hr[(d + 1) >> 6], (d + 1) & 63);           \
        a2 += vv[j] * rlane(hr[(d + 2) >> 6], (d + 2) & 63);           \
        a3 += vv[j] * rlane(hr[(d + 3) >> 6], (d + 3) & 63);           \
      }                                                                \
    }
    if (half == 0) {
#pragma unroll
      for (int f4 = 0; f4 < 25; ++f4) EPI_F4(f4)
    } else {
#pragma unroll
      for (int f4 = 25; f4 < 49; ++f4) EPI_F4(f4)
    }
#undef EPI_F4
    if (half) {
      float* pp = &sm->u.p2.g.f.part[ch * 5];
      pp[0] = a0; pp[1] = a1; pp[2] = a2; pp[3] = a3;
    }
    __syncthreads();
    if (tid < 512) {
      const float* pp = &sm->u.p2.g.f.part[tid * 5];
      a0 += pp[0]; a1 += pp[1]; a2 += pp[2]; a3 += pp[3];
      float y = 0.f;
#pragma unroll
      for (int s = 0; s < 4; ++s) {
        float pre = w1[s * 4 + 0] * a0 + w1[s * 4 + 1] * a1 + w1[s * 4 + 2] * a2
                  + w1[s * 4 + 3] * a3;
        y += w2[s] * fmaxf(pre, 0.f);
      }
      sm->u.p2.Y[tid] = y;
    }
  }
  __syncthreads();
  // z[u] = relu(sum_c y[c] fw1[u][c]) : 32 lanes per u, half-wave reduce
  {
    int u = tid >> 5, lc = tid & 31;
    float a = 0.f;
#pragma unroll
    for (int k = 0; k < 16; ++k) {
      int c = lc + 32 * k;
      a += sm->u.p2.Y[c] * fw1[u * 512 + c];
    }
    a += __shfl_xor(a, 1, 64);
    a += __shfl_xor(a, 2, 64);
    a += __shfl_xor(a, 4, 64);
    a += __shfl_xor(a, 8, 64);
    a += __shfl_xor(a, 16, 64);
    if (lc == 0) sm->u.p2.Y[512 + u] = fmaxf(a, 0.f);
  }
  __syncthreads();
  // gate[c] = sigmoid(sum_u z[u] fw2[c][u])
  if (tid < 512) {
    const float4* f2r = (const float4*)(fw2 + tid * 32);
    float za = 0.f;
#pragma unroll
    for (int u4 = 0; u4 < 8; ++u4) {
      float4 fv = f2r[u4];
      za += fv.x * sm->u.p2.Y[512 + u4 * 4 + 0];
      za += fv.y * sm->u.p2.Y[512 + u4 * 4 + 1];
      za += fv.z * sm->u.p2.Y[512 + u4 * 4 + 2];
      za += fv.w * sm->u.p2.Y[512 + u4 * 4 + 3];
    }
    float g = 1.f / (1.f + __expf(-za));
    sm->u.p2.Y[tid] = g;  // y dead -> reuse as gate
  }
  __syncthreads();
  // out = x * gate  (float4, coalesced; 49 float4 per channel)
  {
    const float4* xi = (const float4*)xb;
    float4* oo = (float4*)(out + (size_t)b * 100352);
#pragma unroll
    for (int t = 0; t < 25; ++t) {
      int v = tid + t * 1024;
      if (v < 25088) {
        float4 q = xi[v];
        float g = sm->u.p2.Y[v / 49];
        oo[v] = make_float4(q.x * g, q.y * g, q.z * g, q.w * g);
      }
    }
  }
}

extern "C" void kernel_launch(void* const* d_in, const int* in_sizes, int n_in,
                              void* d_out, int out_size, void* d_ws, size_t ws_size,
                              hipStream_t stream) {
  (void)in_sizes; (void)n_in; (void)d_ws; (void)ws_size; (void)out_size;
  const float* x   = (const float*)d_in[0];
  // d_in[1] = A0: unused (overwritten before first use in the reference)
  const float* B0  = (const float*)d_in[2];
  const float* C0  = (const float*)d_in[3];
  const float* w1  = (const float*)d_in[4];
  const float* w2  = (const float*)d_in[5];
  const float* fw1 = (const float*)d_in[6];
  const float* fw2 = (const float*)d_in[7];
  float* out = (float*)d_out;

  size_t shmem = sizeof(SMem);  // ~163 KB, fits gfx950's 160 KiB LDS
  hipFuncSetAttribute((const void*)dese_kernel,
                      hipFuncAttributeMaxDynamicSharedMemorySize, (int)shmem);
  hipLaunchKernelGGL(dese_kernel, dim3(256), dim3(1024), shmem, stream,
                     x, B0, C0, w1, w2, fw1, fw2, out);
}

// Round 4
// 308.155 us; speedup vs baseline: 1.5170x; 1.1820x over previous
//
#include <hip/hip_runtime.h>

// DeSELayer: per-sample CP-ALS(rank4, 20 it) -> rank_fc -> SE fc -> sigmoid gate.
// Gram-trick: iterations run on Gram = T0^T T0 (196x196).
// 1 workgroup (1024 thr) per sample; grid = 256 = #CUs.
// R3: phase-1 Gram via MFMA split-bf16.
// R4: phase-2 Y = Gram*H via MFMA (A-frags of Gram in registers per wave).
// R5: phase-1 frags direct from global; 2x4 register-blocked tiles;
//     closed-form register 4x4 inverse.
// R6: ATA fused into Y phase; async-stage phase 1.
// R7: (a) v_cvt_pk_bf16_f32 for ALL fp32->bf16 hi/lo splits (4x fewer ops);
//     (b) phase-1: 8 chunks of 64ch, double-buffered frag LDS, 1 barrier per
//     chunk, MFMA || convert || load-issue overlap;
//     (c) factor_update: BtB/CtC via register shfl_xor gram (no LDS chains),
//     ctc_old carried in register across iterations, float4 B/C loads,
//     cvt_pk scatter. Wave-13 CtC hoist removed.

#define EPSV 1e-6f

#define SM_ATA  104   // 16 floats inside Sm[]

typedef __attribute__((ext_vector_type(8))) short short8;
typedef __attribute__((ext_vector_type(4))) float float4v;

struct SMem {
  union {
    struct {                      // ---- phase 1 ----
      short xhi[2 * 26 * 64 * 8]; // [buf][kstep s(2)][ptile(13)][lane][8 ch] bf16 hi
      short xlo[2 * 26 * 64 * 8]; // 53,248 B each
    } p1;
    struct {                      // ---- phase 2 ----
      union {
        float gram[196 * 197];    // 154,448 B; dead after A-frag build
        struct {                  // live after A-frag build
          short fh[7 * 64 * 8];   // H B-fragments bf16 hi: [kb][lane][8]
          short fl[7 * 64 * 8];   // H B-fragments bf16 lo
          float part[512 * 5];    // epilogue partial sums (stride 5)
        } f;
      } g;
      float H[196 * 5];           // stride 5
      float Y[196 * 5];           // stride 5; epilogue: y[512] @0, z[32] @512
    } p2;
  } u;
  float B[56];                    // B[j][r] flat j*4+r (16B-aligned rows)
  float C[56];
  float Sm[120];                  // SM_ATA window
};

__device__ __forceinline__ float rlane(float v, int l) {
  return __uint_as_float(__builtin_amdgcn_readlane(__float_as_uint(v), l));
}
__device__ __forceinline__ void fence_lds() { __threadfence_block(); }

// packed fp32x2 -> bf16x2 (RNE); lo16 = first arg, hi16 = second arg
__device__ __forceinline__ unsigned cvtpk(float a, float b) {
  unsigned r;
  asm("v_cvt_pk_bf16_f32 %0, %1, %2" : "=v"(r) : "v"(a), "v"(b));
  return r;
}
__device__ __forceinline__ float asf(unsigned u) { return __uint_as_float(u); }

// (V^T V)[r][s] per lane (pattern repeats across lanes); V = 14x4 flat in LDS
__device__ __forceinline__ float gram16(const float* V, int l) {
  int r = (l >> 2) & 3, s = l & 3;
  float a = 0.f;
#pragma unroll
  for (int j = 0; j < 14; ++j) a += V[j * 4 + r] * V[j * 4 + s];
  return a;
}

// register gram: v at lane 4j+r = V[j][r] (lanes>=56 MUST be zero).
// Returns at lane t: (V^T V)[(t>>2)&3][t&3] (valid for t<16 pattern; symmetric).
__device__ __forceinline__ float regGram(float v, int l) {
  float S0 = v * v;
  S0 += __shfl_xor(S0, 4, 64);  S0 += __shfl_xor(S0, 8, 64);
  S0 += __shfl_xor(S0, 16, 64); S0 += __shfl_xor(S0, 32, 64);
  float S1 = v * __shfl_xor(v, 1, 64);
  S1 += __shfl_xor(S1, 4, 64);  S1 += __shfl_xor(S1, 8, 64);
  S1 += __shfl_xor(S1, 16, 64); S1 += __shfl_xor(S1, 32, 64);
  float S2 = v * __shfl_xor(v, 2, 64);
  S2 += __shfl_xor(S2, 4, 64);  S2 += __shfl_xor(S2, 8, 64);
  S2 += __shfl_xor(S2, 16, 64); S2 += __shfl_xor(S2, 32, 64);
  float S3 = v * __shfl_xor(v, 3, 64);
  S3 += __shfl_xor(S3, 4, 64);  S3 += __shfl_xor(S3, 8, 64);
  S3 += __shfl_xor(S3, 16, 64); S3 += __shfl_xor(S3, 32, 64);
  int e = ((l >> 2) ^ l) & 3;
  float x = (e & 1) ? S1 : S0;
  float y = (e & 1) ? S3 : S2;
  return (e & 2) ? y : x;
}

// 2-bit select of 4 candidates (static candidates, runtime k) -> 3 cndmask
__device__ __forceinline__ float sel4(float a, float b, float c, float d, int k) {
  float x = (k & 1) ? b : a;
  float y = (k & 1) ? d : c;
  return (k & 2) ? y : x;
}

// All lanes: myG at lane t=i*4+j holds G[i][j] (valid t<16).
// Produces full inverse in gv[16] (row-major), all indices STATIC -> registers.
__device__ __forceinline__ void ginv_lanes(float myG, float gv[16]) {
  const float a00 = rlane(myG, 0),  a01 = rlane(myG, 1),  a02 = rlane(myG, 2),  a03 = rlane(myG, 3);
  const float a10 = rlane(myG, 4),  a11 = rlane(myG, 5),  a12 = rlane(myG, 6),  a13 = rlane(myG, 7);
  const float a20 = rlane(myG, 8),  a21 = rlane(myG, 9),  a22 = rlane(myG, 10), a23 = rlane(myG, 11);
  const float a30 = rlane(myG, 12), a31 = rlane(myG, 13), a32 = rlane(myG, 14), a33 = rlane(myG, 15);
  const float s0 = a00*a11 - a10*a01, s1 = a00*a12 - a10*a02, s2 = a00*a13 - a10*a03;
  const float s3 = a01*a12 - a11*a02, s4 = a01*a13 - a11*a03, s5 = a02*a13 - a12*a03;
  const float c5 = a22*a33 - a32*a23, c4 = a21*a33 - a31*a23, c3 = a21*a32 - a31*a22;
  const float c2 = a20*a33 - a30*a23, c1 = a20*a32 - a30*a22, c0 = a20*a31 - a30*a21;
  const float det = s0*c5 - s1*c4 + s2*c3 + s3*c2 - s4*c1 + s5*c0;
  const float rd = 1.0f / det;
  gv[0]  = ( a11*c5 - a12*c4 + a13*c3) * rd;
  gv[1]  = (-a01*c5 + a02*c4 - a03*c3) * rd;
  gv[2]  = ( a31*s5 - a32*s4 + a33*s3) * rd;
  gv[3]  = (-a21*s5 + a22*s4 - a23*s3) * rd;
  gv[4]  = (-a10*c5 + a12*c2 - a13*c1) * rd;
  gv[5]  = ( a00*c5 - a02*c2 + a03*c1) * rd;
  gv[6]  = (-a30*s5 + a32*s2 - a33*s1) * rd;
  gv[7]  = ( a20*s5 - a22*s2 + a23*s1) * rd;
  gv[8]  = ( a10*c4 - a11*c2 + a13*c0) * rd;
  gv[9]  = (-a00*c4 + a01*c2 - a03*c0) * rd;
  gv[10] = ( a30*s4 - a31*s2 + a33*s0) * rd;
  gv[11] = (-a20*s4 + a21*s2 - a23*s0) * rd;
  gv[12] = (-a10*c3 + a11*c1 - a12*c0) * rd;
  gv[13] = ( a00*c3 - a01*c1 + a02*c0) * rd;
  gv[14] = (-a30*s3 + a31*s1 - a32*s0) * rd;
  gv[15] = ( a20*s3 - a21*s1 + a22*s0) * rd;
}

// wave 0: H[p][r] = sum_s B[j][s]C[k][s] * Ginv[s][r] (Ginv in regs, static idx).
// Writes fp32 H (stride 5); if scatter, also bf16 hi/lo into B-fragment arrays.
__device__ __forceinline__ void computeH_scatter(SMem* sm, int l, const float gv[16],
                                                 bool scatter) {
#pragma unroll
  for (int k4 = 0; k4 < 4; ++k4) {
    int p = l + 64 * k4;
    if (p < 196) {
      int j = p / 14, kk = p - j * 14;
      float4 Bj = *(const float4*)&sm->B[j * 4];
      float4 Ck = *(const float4*)&sm->C[kk * 4];
      float kr0 = Bj.x * Ck.x, kr1 = Bj.y * Ck.y, kr2 = Bj.z * Ck.z, kr3 = Bj.w * Ck.w;
      float h0 = kr0 * gv[0] + kr1 * gv[4] + kr2 * gv[8]  + kr3 * gv[12];
      float h1 = kr0 * gv[1] + kr1 * gv[5] + kr2 * gv[9]  + kr3 * gv[13];
      float h2 = kr0 * gv[2] + kr1 * gv[6] + kr2 * gv[10] + kr3 * gv[14];
      float h3 = kr0 * gv[3] + kr1 * gv[7] + kr2 * gv[11] + kr3 * gv[15];
      float* Hp = &sm->u.p2.H[p * 5];
      Hp[0] = h0; Hp[1] = h1; Hp[2] = h2; Hp[3] = h3;
      if (scatter) {
        int fib = ((p >> 5) * 64 + ((p >> 3) & 3) * 16) * 8 + (p & 7);
        unsigned pa = cvtpk(h0, h1), pb = cvtpk(h2, h3);
        float la0 = h0 - asf(pa << 16), la1 = h1 - asf(pa & 0xFFFF0000u);
        float lb0 = h2 - asf(pb << 16), lb1 = h3 - asf(pb & 0xFFFF0000u);
        unsigned qa = cvtpk(la0, la1), qb = cvtpk(lb0, lb1);
        short* fh = sm->u.p2.g.f.fh;
        short* fl = sm->u.p2.g.f.fl;
        fh[fib]      = (short)pa; fh[fib + 8]  = (short)(pa >> 16);
        fh[fib + 16] = (short)pb; fh[fib + 24] = (short)(pb >> 16);
        fl[fib]      = (short)qa; fl[fib + 8]  = (short)(qa >> 16);
        fl[fib + 16] = (short)qb; fl[fib + 24] = (short)(qb >> 16);
      }
    }
  }
}

// returns CtC pattern value (to carry as ctc_prev)
__device__ __forceinline__ float initial_H(SMem* sm, int l) {
  float btb = gram16(sm->B, l);
  float ctc = gram16(sm->C, l);
  float dgl = ((l >> 2) == (l & 3)) ? EPSV : 0.f;
  float gv[16];
  ginv_lanes(btb * ctc + dgl, gv);
  if (l < 16) sm->Sm[SM_ATA + l] = 0.f;   // ready for first Y-phase atomics
  computeH_scatter(sm, l, gv, true);
  return ctc;
}

// wave 0 (all 64 lanes): ATA in Sm[ATA] (zeroed after read), ctc_prev carried
// in register. Updates B, C, then next H. Returns new CtC pattern value.
__device__ __forceinline__ float factor_update(SMem* sm, int l, float ctc_prev,
                                               bool last) {
  const int jj = l >> 2, r = l & 3;
  const float dgl = ((l >> 2) == (l & 3)) ? EPSV : 0.f;
  const float ata = sm->Sm[SM_ATA + (l & 15)];
  if (l < 16) sm->Sm[SM_ATA + l] = 0.f;   // next iter's atomics start post-barrier
  float gv[16];
  // --- B update: G_B = ATA o CtC(old) + eps ---
  ginv_lanes(ata * ctc_prev + dgl, gv);
  float m = 0.f;
  if (l < 56) {
#pragma unroll
    for (int k = 0; k < 14; ++k) m += sm->u.p2.Y[(jj * 14 + k) * 5 + r] * sm->C[k * 4 + r];
  }
  float bn = 0.f;
#pragma unroll
  for (int e = 0; e < 4; ++e) {
    float me = e ? __shfl_xor(m, e, 64) : m;             // M[jj][r^e]
    float coef = sel4(gv[((0 ^ e) << 2) + 0], gv[((1 ^ e) << 2) + 1],
                      gv[((2 ^ e) << 2) + 2], gv[((3 ^ e) << 2) + 3], r); // Ginv[r^e][r]
    bn += me * coef;
  }
  bn = (l < 56) ? bn : 0.f;
  if (l < 56) sm->B[l] = bn;
  fence_lds();
  const float btb_new = regGram(bn, l);
  // --- C update: G_C = ATA o BtB(new) + eps ---
  ginv_lanes(ata * btb_new + dgl, gv);
  float m2 = 0.f;
  if (l < 56) {
#pragma unroll
    for (int j = 0; j < 14; ++j) m2 += sm->u.p2.Y[(j * 14 + jj) * 5 + r] * sm->B[j * 4 + r];
  }
  float cn = 0.f;
#pragma unroll
  for (int e = 0; e < 4; ++e) {
    float me = e ? __shfl_xor(m2, e, 64) : m2;
    float coef = sel4(gv[((0 ^ e) << 2) + 0], gv[((1 ^ e) << 2) + 1],
                      gv[((2 ^ e) << 2) + 2], gv[((3 ^ e) << 2) + 3], r);
    cn += me * coef;
  }
  cn = (l < 56) ? cn : 0.f;
  if (l < 56) sm->C[l] = cn;
  fence_lds();
  const float ctc_new = regGram(cn, l);
  // --- next-iteration H: G_A = BtB(new) o CtC(new) + eps ---
  ginv_lanes(btb_new * ctc_new + dgl, gv);
  computeH_scatter(sm, l, gv, !last);
  return ctc_new;
}

extern "C" __global__ void __launch_bounds__(1024, 4)
dese_kernel(const float* __restrict__ x, const float* __restrict__ B0,
            const float* __restrict__ C0, const float* __restrict__ w1,
            const float* __restrict__ w2, const float* __restrict__ fw1,
            const float* __restrict__ fw2, float* __restrict__ out) {
  extern __shared__ char smraw[];
  SMem* sm = (SMem*)smraw;
  const int tid = threadIdx.x;
  const int b = blockIdx.x;
  const int wv = tid >> 6;
  const int lane = tid & 63;
  const float* xb = x + (size_t)b * 100352;

  // load per-sample B0, C0 (A0 is dead: first ALS step overwrites A)
  if (tid < 56) sm->B[tid] = B0[b * 56 + tid];
  if (tid >= 64 && tid < 120) sm->C[tid - 64] = C0[b * 56 + (tid - 64)];

  // ================= Phase 1: Gram = X X^T via MFMA split-bf16 =================
  // X = T0^T (196 spatial x 512 ch), padded to 208 rows (13 tiles of 16).
  // 2x4 register-blocked tiles; 8 chunks of 64 ch; double-buffered frag LDS;
  // per chunk: MFMA(cur) || convert(next) || issue loads(next+1); 1 barrier.
  {
    const int R = (wv >= 4) + (wv >= 7) + (wv >= 10) + (wv >= 12) + (wv >= 14) + (wv >= 15);
    const int base = (R == 0) ? 0 : (R == 1) ? 4 : (R == 2) ? 7 : (R == 3) ? 10
                   : (R == 4) ? 12 : (R == 5) ? 14 : 15;
    const int I0 = 2 * R;
    const int J0 = I0 + 4 * (wv - base);
    const int IC1 = (I0 + 1 <= 12) ? I0 + 1 : 12;   // clamped read index
    const bool iok1 = (I0 + 1 <= 12);

    // staging: wave wv<13 handles units (s=0,pt=wv) and (s=1,pt=wv)
    const int pp_ = wv * 16 + (lane & 15);          // spatial row this lane stages
    const int co_ = (lane >> 4) * 8;                // channel octet base in kstep
    const bool stg = (wv < 13);

    float xr[2][8];
#define ISSUE_LOADS(CHUNK)                                                     \
    {                                                                          \
      _Pragma("unroll")                                                        \
      for (int s2 = 0; s2 < 2; ++s2) {                                         \
        int chb = (CHUNK) * 64 + s2 * 32 + co_;                                \
        _Pragma("unroll")                                                      \
        for (int ii = 0; ii < 8; ++ii)                                         \
          xr[s2][ii] = (pp_ < 196) ? xb[(size_t)(chb + ii) * 196 + pp_] : 0.f; \
      }                                                                        \
    }
#define CONVERT_STORE(BUF)                                                     \
    {                                                                          \
      _Pragma("unroll")                                                        \
      for (int s2 = 0; s2 < 2; ++s2) {                                         \
        unsigned hp[4], lp[4];                                                 \
        _Pragma("unroll")                                                      \
        for (int q = 0; q < 4; ++q) {                                          \
          float v0 = xr[s2][2 * q], v1 = xr[s2][2 * q + 1];                    \
          unsigned h = cvtpk(v0, v1);                                          \
          float l0 = v0 - asf(h << 16), l1 = v1 - asf(h & 0xFFFF0000u);        \
          hp[q] = h; lp[q] = cvtpk(l0, l1);                                    \
        }                                                                      \
        int fidx = (((BUF) * 26) + s2 * 13 + wv) * 64 + lane;                  \
        *(uint4*)&sm->u.p1.xhi[fidx * 8] = make_uint4(hp[0], hp[1], hp[2], hp[3]); \
        *(uint4*)&sm->u.p1.xlo[fidx * 8] = make_uint4(lp[0], lp[1], lp[2], lp[3]); \
      }                                                                        \
    }

    float4v acc0[4], acc1[4];
#pragma unroll
    for (int i = 0; i < 4; ++i) {
      acc0[i] = (float4v){0.f, 0.f, 0.f, 0.f};
      acc1[i] = (float4v){0.f, 0.f, 0.f, 0.f};
    }

    if (stg) {
      ISSUE_LOADS(0)
      CONVERT_STORE(0)
      ISSUE_LOADS(1)
    }
    __syncthreads();   // buf0 ready

    for (int c = 0; c < 8; ++c) {
      const int buf = c & 1;
      // ---- MFMA on buf: 2 ksteps x (2 row-frags x 4 col-frags) ----
#pragma unroll
      for (int s = 0; s < 2; ++s) {
        const int ub = buf * 26 + s * 13;
        const short8 aH0 = *(const short8*)&sm->u.p1.xhi[((ub + I0)  * 64 + lane) * 8];
        const short8 aL0 = *(const short8*)&sm->u.p1.xlo[((ub + I0)  * 64 + lane) * 8];
        const short8 aH1 = *(const short8*)&sm->u.p1.xhi[((ub + IC1) * 64 + lane) * 8];
        const short8 aL1 = *(const short8*)&sm->u.p1.xlo[((ub + IC1) * 64 + lane) * 8];
#pragma unroll
        for (int j = 0; j < 4; ++j) {
          const int J = J0 + j;
          if (J <= 12) {                            // wave-uniform
            const short8 bH = *(const short8*)&sm->u.p1.xhi[((ub + J) * 64 + lane) * 8];
            const short8 bL = *(const short8*)&sm->u.p1.xlo[((ub + J) * 64 + lane) * 8];
            acc0[j] = __builtin_amdgcn_mfma_f32_16x16x32_bf16(aH0, bH, acc0[j], 0, 0, 0);
            acc0[j] = __builtin_amdgcn_mfma_f32_16x16x32_bf16(aH0, bL, acc0[j], 0, 0, 0);
            acc0[j] = __builtin_amdgcn_mfma_f32_16x16x32_bf16(aL0, bH, acc0[j], 0, 0, 0);
            if (iok1 && I0 + 1 <= J) {              // wave-uniform
              acc1[j] = __builtin_amdgcn_mfma_f32_16x16x32_bf16(aH1, bH, acc1[j], 0, 0, 0);
              acc1[j] = __builtin_amdgcn_mfma_f32_16x16x32_bf16(aH1, bL, acc1[j], 0, 0, 0);
              acc1[j] = __builtin_amdgcn_mfma_f32_16x16x32_bf16(aL1, bH, acc1[j], 0, 0, 0);
            }
          }
        }
      }
      // ---- convert next chunk into other buf; issue chunk c+2 loads ----
      if (stg && c + 1 < 8) CONVERT_STORE(buf ^ 1)
      if (stg && c + 2 < 8) ISSUE_LOADS(c + 2)
      __syncthreads();   // next buf ready; cur buf reads done before overwrite
    }
#undef ISSUE_LOADS
#undef CONVERT_STORE
    // ---- write acc -> gram (C/D layout: col=lane&15, row=quad*4+reg) + mirror ----
    {
      int col = lane & 15, quad = lane >> 4;
#define WRITE_TILE(ACC, I)                                          \
      {                                                             \
        int pc = (J0 + j) * 16 + col;                               \
        _Pragma("unroll")                                           \
        for (int reg = 0; reg < 4; ++reg) {                         \
          int pr = (I) * 16 + quad * 4 + reg;                       \
          if (pr < 196 && pc < 196) {                               \
            float v = ACC[j][reg];                                  \
            sm->u.p2.g.gram[pr * 197 + pc] = v;                     \
            sm->u.p2.g.gram[pc * 197 + pr] = v;                     \
          }                                                         \
        }                                                           \
      }
#pragma unroll
      for (int j = 0; j < 4; ++j) {
        const int J = J0 + j;
        if (J <= 12) {
          WRITE_TILE(acc0, I0)
          if (iok1 && I0 + 1 <= J) WRITE_TILE(acc1, I0 + 1)
        }
      }
#undef WRITE_TILE
    }
  }
  __syncthreads();

  // ============ A-fragment build: wave J holds Gram row-block J in regs ========
  // A-frag (16x16x32): lane l, elem i -> A[m=l&15, k=(l>>4)*8+i] = G[J*16+m, kb*32+k].
  short8 afh[7], afl[7];
  if (wv < 13) {
    const int m = wv * 16 + (lane & 15);
    const int mok = (m < 196);
    const int kq = (lane >> 4) * 8;
#pragma unroll
    for (int kb = 0; kb < 7; ++kb) {
      unsigned hw[4], lw[4];
#pragma unroll
      for (int q = 0; q < 4; ++q) {
        int k0 = kb * 32 + kq + 2 * q;
        float v0 = (mok && k0 < 196)     ? sm->u.p2.g.gram[m * 197 + k0]     : 0.f;
        float v1 = (mok && k0 + 1 < 196) ? sm->u.p2.g.gram[m * 197 + k0 + 1] : 0.f;
        unsigned h = cvtpk(v0, v1);
        float l0 = v0 - asf(h << 16), l1 = v1 - asf(h & 0xFFFF0000u);
        hw[q] = h; lw[q] = cvtpk(l0, l1);
      }
      uint4 th = make_uint4(hw[0], hw[1], hw[2], hw[3]);
      uint4 tl = make_uint4(lw[0], lw[1], lw[2], lw[3]);
      afh[kb] = *(short8*)&th;
      afl[kb] = *(short8*)&tl;
    }
  }
  __syncthreads();  // gram fully consumed; its region may now be reused
  // zero-fill H B-fragment arrays once (pads stay zero forever)
  {
    unsigned* z = (unsigned*)sm->u.p2.g.f.fh;  // fh+fl contiguous: 3584 u32
#pragma unroll
    for (int t = 0; t < 4; ++t) {
      int idx = tid + 1024 * t;
      if (idx < 3584) z[idx] = 0u;
    }
  }
  __syncthreads();

  // ================= Phase 2: 19 ALS iteration bodies on Gram =================
  float ctc_prev = 0.f;
  if (tid < 64) ctc_prev = initial_H(sm, lane);
  __syncthreads();

  for (int it = 0; it < 19; ++it) {
    // ---- Y = Gram*H via MFMA + fused ATA partials ----
    if (wv < 13) {
      float4v ac0 = {0.f, 0.f, 0.f, 0.f}, ac1 = {0.f, 0.f, 0.f, 0.f};
#pragma unroll
      for (int kb = 0; kb < 7; ++kb) {
        const short8 bh = *(const short8*)&sm->u.p2.g.f.fh[(kb * 64 + lane) * 8];
        const short8 bl = *(const short8*)&sm->u.p2.g.f.fl[(kb * 64 + lane) * 8];
        if (kb & 1) {
          ac1 = __builtin_amdgcn_mfma_f32_16x16x32_bf16(afh[kb], bh, ac1, 0, 0, 0);
          ac1 = __builtin_amdgcn_mfma_f32_16x16x32_bf16(afh[kb], bl, ac1, 0, 0, 0);
          ac1 = __builtin_amdgcn_mfma_f32_16x16x32_bf16(afl[kb], bh, ac1, 0, 0, 0);
        } else {
          ac0 = __builtin_amdgcn_mfma_f32_16x16x32_bf16(afh[kb], bh, ac0, 0, 0, 0);
          ac0 = __builtin_amdgcn_mfma_f32_16x16x32_bf16(afh[kb], bl, ac0, 0, 0, 0);
          ac0 = __builtin_amdgcn_mfma_f32_16x16x32_bf16(afl[kb], bh, ac0, 0, 0, 0);
        }
      }
      float4v acc = ac0 + ac1;
      const int col = lane & 15;
      const int quad = lane >> 4;
      const int row0 = wv * 16 + quad * 4;
      if (col < 4) {
#pragma unroll
        for (int reg = 0; reg < 4; ++reg) {
          int pr = row0 + reg;
          if (pr < 196) sm->u.p2.Y[pr * 5 + col] = acc[reg];
        }
        float pa0 = 0.f, pa1 = 0.f, pa2 = 0.f, pa3 = 0.f;
#pragma unroll
        for (int reg = 0; reg < 4; ++reg) {
          int pr = row0 + reg;
          if (pr < 196) {
            float yv = acc[reg];
            pa0 += sm->u.p2.H[pr * 5 + 0] * yv;
            pa1 += sm->u.p2.H[pr * 5 + 1] * yv;
            pa2 += sm->u.p2.H[pr * 5 + 2] * yv;
            pa3 += sm->u.p2.H[pr * 5 + 3] * yv;
          }
        }
        pa0 += __shfl_xor(pa0, 16, 64); pa0 += __shfl_xor(pa0, 32, 64);
        pa1 += __shfl_xor(pa1, 16, 64); pa1 += __shfl_xor(pa1, 32, 64);
        pa2 += __shfl_xor(pa2, 16, 64); pa2 += __shfl_xor(pa2, 32, 64);
        pa3 += __shfl_xor(pa3, 16, 64); pa3 += __shfl_xor(pa3, 32, 64);
        if (quad == 0) {
          atomicAdd(&sm->Sm[SM_ATA + 0 * 4 + col], pa0);
          atomicAdd(&sm->Sm[SM_ATA + 1 * 4 + col], pa1);
          atomicAdd(&sm->Sm[SM_ATA + 2 * 4 + col], pa2);
          atomicAdd(&sm->Sm[SM_ATA + 3 * 4 + col], pa3);
        }
      }
    }
    __syncthreads();
    if (tid < 64) ctc_prev = factor_update(sm, lane, ctc_prev, it == 18);
    __syncthreads();
  }

  // ================= Epilogue =================
  // y[i] = w2 . relu(w1 . (T0[i,:] H))  for i in 0..511; 2 threads per channel.
  {
    float hr[13];  // dense H (4p+r) spread over lanes, all waves load
#pragma unroll
    for (int k = 0; k < 13; ++k) {
      int d = 64 * k + lane;
      hr[k] = (d < 784) ? sm->u.p2.H[(d >> 2) * 5 + (d & 3)] : 0.f;
    }
    const int ch = tid & 511;
    const int half = tid >> 9;   // wave-uniform
    const float4* row = (const float4*)(xb + ch * 196);
    float a0 = 0.f, a1 = 0.f, a2 = 0.f, a3 = 0.f;
#define EPI_F4(F4)                                                     \
    {                                                                  \
      float4 v = row[(F4)];                                            \
      float vv[4] = {v.x, v.y, v.z, v.w};                              \
      _Pragma("unroll")                                                \
      for (int j = 0; j < 4; ++j) {                                    \
        int d = 16 * (F4) + 4 * j;                                     \
        a0 += vv[j] * rlane(hr[(d + 0) >> 6], (d + 0) & 63);           \
        a1 += vv[j] * rlane(hr[(d + 1) >> 6], (d + 1) & 63);           \
        a2 += vv[j] * rlane(hr[(d + 2) >> 6], (d + 2) & 63);           \
        a3 += vv[j] * rlane(hr[(d + 3) >> 6], (d + 3) & 63);           \
      }                                                                \
    }
    if (half == 0) {
#pragma unroll
      for (int f4 = 0; f4 < 25; ++f4) EPI_F4(f4)
    } else {
#pragma unroll
      for (int f4 = 25; f4 < 49; ++f4) EPI_F4(f4)
    }
#undef EPI_F4
    if (half) {
      float* pp = &sm->u.p2.g.f.part[ch * 5];
      pp[0] = a0; pp[1] = a1; pp[2] = a2; pp[3] = a3;
    }
    __syncthreads();
    if (tid < 512) {
      const float* pp = &sm->u.p2.g.f.part[tid * 5];
      a0 += pp[0]; a1 += pp[1]; a2 += pp[2]; a3 += pp[3];
      float y = 0.f;
#pragma unroll
      for (int s = 0; s < 4; ++s) {
        float pre = w1[s * 4 + 0] * a0 + w1[s * 4 + 1] * a1 + w1[s * 4 + 2] * a2
                  + w1[s * 4 + 3] * a3;
        y += w2[s] * fmaxf(pre, 0.f);
      }
      sm->u.p2.Y[tid] = y;
    }
  }
  __syncthreads();
  // z[u] = relu(sum_c y[c] fw1[u][c]) : 32 lanes per u, half-wave reduce
  {
    int u = tid >> 5, lc = tid & 31;
    float a = 0.f;
#pragma unroll
    for (int k = 0; k < 16; ++k) {
      int c = lc + 32 * k;
      a += sm->u.p2.Y[c] * fw1[u * 512 + c];
    }
    a += __shfl_xor(a, 1, 64);
    a += __shfl_xor(a, 2, 64);
    a += __shfl_xor(a, 4, 64);
    a += __shfl_xor(a, 8, 64);
    a += __shfl_xor(a, 16, 64);
    if (lc == 0) sm->u.p2.Y[512 + u] = fmaxf(a, 0.f);
  }
  __syncthreads();
  // gate[c] = sigmoid(sum_u z[u] fw2[c][u])
  if (tid < 512) {
    const float4* f2r = (const float4*)(fw2 + tid * 32);
    float za = 0.f;
#pragma unroll
    for (int u4 = 0; u4 < 8; ++u4) {
      float4 fv = f2r[u4];
      za += fv.x * sm->u.p2.Y[512 + u4 * 4 + 0];
      za += fv.y * sm->u.p2.Y[512 + u4 * 4 + 1];
      za += fv.z * sm->u.p2.Y[512 + u4 * 4 + 2];
      za += fv.w * sm->u.p2.Y[512 + u4 * 4 + 3];
    }
    float g = 1.f / (1.f + __expf(-za));
    sm->u.p2.Y[tid] = g;  // y dead -> reuse as gate
  }
  __syncthreads();
  // out = x * gate  (float4, coalesced; 49 float4 per channel)
  {
    const float4* xi = (const float4*)xb;
    float4* oo = (float4*)(out + (size_t)b * 100352);
#pragma unroll
    for (int t = 0; t < 25; ++t) {
      int v = tid + t * 1024;
      if (v < 25088) {
        float4 q = xi[v];
        float g = sm->u.p2.Y[v / 49];
        oo[v] = make_float4(q.x * g, q.y * g, q.z * g, q.w * g);
      }
    }
  }
}

extern "C" void kernel_launch(void* const* d_in, const int* in_sizes, int n_in,
                              void* d_out, int out_size, void* d_ws, size_t ws_size,
                              hipStream_t stream) {
  (void)in_sizes; (void)n_in; (void)d_ws; (void)ws_size; (void)out_size;
  const float* x   = (const float*)d_in[0];
  // d_in[1] = A0: unused (overwritten before first use in the reference)
  const float* B0  = (const float*)d_in[2];
  const float* C0  = (const float*)d_in[3];
  const float* w1  = (const float*)d_in[4];
  const float* w2  = (const float*)d_in[5];
  const float* fw1 = (const float*)d_in[6];
  const float* fw2 = (const float*)d_in[7];
  float* out = (float*)d_out;

  size_t shmem = sizeof(SMem);  // ~163 KB, fits gfx950's 160 KiB LDS
  hipFuncSetAttribute((const void*)dese_kernel,
                      hipFuncAttributeMaxDynamicSharedMemorySize, (int)shmem);
  hipLaunchKernelGGL(dese_kernel, dim3(256), dim3(1024), shmem, stream,
                     x, B0, C0, w1, w2, fw1, fw2, out);
}